// Round 15
// baseline (452.606 us; speedup 1.0000x reference)
//
#include <hip/hip_runtime.h>
#include <hip/hip_bf16.h>
#include <stdint.h>

typedef short short8 __attribute__((ext_vector_type(8)));
typedef float f32x4 __attribute__((ext_vector_type(4)));
typedef float fvec4 __attribute__((ext_vector_type(4)));
typedef unsigned short us4 __attribute__((ext_vector_type(4)));
typedef unsigned short us8 __attribute__((ext_vector_type(8)));

// native float->bf16 (RNE)
static __device__ __forceinline__ unsigned short f2bf(float f) {
  return __bfloat16_as_ushort(__float2bfloat16(f));
}

static __device__ __forceinline__ float bf2f(unsigned short u) {
  union { uint32_t u; float f; } v; v.u = (uint32_t)u << 16;
  return v.f;
}

// fast ELU: __expf -> v_exp_f32. |err| ~1e-7, fine vs 2e-2 threshold.
static __device__ __forceinline__ float elu_f(float v) {
  return v > 0.0f ? v : __expf(v) - 1.0f;
}

// Fused prep, three concurrent block ranges:
//   [0, 1024)             : pack all 4 weights into MFMA B-fragment order
//   [1024, 1024+hb)       : histogram dst counts
//   [1024+hb, ...)        : convert x (f32) -> xH (bf16)
__global__ void prep_kernel(const float* __restrict__ W1a, const float* __restrict__ W1b,
                            const float* __restrict__ W2a, const float* __restrict__ W2b,
                            unsigned short* __restrict__ w1aP, unsigned short* __restrict__ w1bP,
                            unsigned short* __restrict__ w2aP, unsigned short* __restrict__ w2bP,
                            const int* __restrict__ col_idx, int* __restrict__ cnt, int E,
                            int hb, const float* __restrict__ x,
                            unsigned short* __restrict__ xH, int xElems) {
  int b = blockIdx.x;
  if (b < 1024) {
    int p = b * 256 + threadIdx.x;
    const float* W; unsigned short* dst; int KT, Nc, q;
    if (p < 65536)       { W = W1a; dst = w1aP; KT = 8;  Nc = 256; q = p; }
    else if (p < 131072) { W = W1b; dst = w1bP; KT = 8;  Nc = 256; q = p - 65536; }
    else if (p < 229376) { W = W2a; dst = w2aP; KT = 12; Nc = 256; q = p - 131072; }
    else                 { W = W2b; dst = w2bP; KT = 8;  Nc = 128; q = p - 229376; }
    int i = q & 7;
    int l = (q >> 3) & 63;
    int rest = q >> 9;
    int kt = rest % KT;
    int nt = rest / KT;
    dst[q] = f2bf(W[(size_t)(kt * 32 + (l >> 4) * 8 + i) * Nc + nt * 16 + (l & 15)]);
  } else if (b < 1024 + hb) {
    int i = (b - 1024) * 256 + threadIdx.x;
    if (i < E) atomicAdd(&cnt[col_idx[i]], 1);
  } else {
    int idx = (b - 1024 - hb) * 256 + threadIdx.x;  // 8-float chunk index
    if (idx * 8 < xElems) {
      const float* src = x + (size_t)idx * 8;
      fvec4 a = *(const fvec4*)src;
      fvec4 c = *(const fvec4*)(src + 4);
      us8 o;
      o[0] = f2bf(a.x); o[1] = f2bf(a.y); o[2] = f2bf(a.z); o[3] = f2bf(a.w);
      o[4] = f2bf(c.x); o[5] = f2bf(c.y); o[6] = f2bf(c.z); o[7] = f2bf(c.w);
      *(us8*)(xH + (size_t)idx * 8) = o;
    }
  }
}

// single-launch scan: each thread serially owns a chunk, one 1024-wide block scan.
__global__ __launch_bounds__(1024) void scan_kernel(const int* __restrict__ cnt,
                                                    int* __restrict__ startA,
                                                    int* __restrict__ offs, int N, int E) {
  __shared__ int partial[1024];
  const int t = threadIdx.x;
  const int chunk = (N + 1023) >> 10;
  const int base = t * chunk;
  int s = 0;
  for (int i = 0; i < chunk; ++i) {
    int idx = base + i;
    if (idx < N) s += cnt[idx];
  }
  partial[t] = s;
  __syncthreads();
  for (int o = 1; o < 1024; o <<= 1) {
    int a = (t >= o) ? partial[t - o] : 0;
    __syncthreads();
    partial[t] += a;
    __syncthreads();
  }
  int run = partial[t] - s;
  for (int i = 0; i < chunk; ++i) {
    int idx = base + i;
    if (idx < N) {
      startA[idx] = run;
      offs[idx] = run;
      run += cnt[idx];
    }
  }
  if (t == 0) startA[N] = E;
}

// dst-sorted edge list: eid[csr_slot] = edge
__global__ void eid_kernel(const int* __restrict__ col_idx, int* __restrict__ offs,
                           int* __restrict__ eid, int E) {
  int i = blockIdx.x * blockDim.x + threadIdx.x;
  if (i < E) eid[atomicAdd(&offs[col_idx[i]], 1)] = i;
}

#define LDA 264   // As stride (bf16)
#define LDX 392   // XB stride (bf16), 384+8
#define LDC 260   // accum stride (f32)
#define NBF 32    // nodes per fused block

// FULLY FUSED kernel: block owns 32 nodes + their contiguous CSR slot range.
// Chunk loop: gather (xH[row]|eattr[eid]) -> GEMM1 -> ELU -> in-LDS segmented
// reduce into block-local f32 accum (no atomics, no global h, no agg buffer).
// Then: mean -> GEMM-u (W1b) + b1b -> [x|u] -> MLP2 -> out. Zero inter-block flow.
__global__ __launch_bounds__(256, 3) void fused_kernel(
    const unsigned short* __restrict__ xH, const int* __restrict__ eid,
    const int* __restrict__ row_idx, const float* __restrict__ eattr,
    const int* __restrict__ startA,
    const float* __restrict__ b1a, const float* __restrict__ b1b,
    const float* __restrict__ b2a, const float* __restrict__ b2b,
    const unsigned short* __restrict__ w1aP, const unsigned short* __restrict__ w1bP,
    const unsigned short* __restrict__ w2aP, const unsigned short* __restrict__ w2bP,
    float* __restrict__ out, int N) {
  __shared__ __align__(16) float accumS[NBF * LDC];       // 33.3 KB (aliased as XB later)
  __shared__ __align__(16) unsigned short As[NBF * LDA];  // 16.9 KB
  __shared__ int startL[NBF + 1];
  __shared__ int eidL[NBF], rowiL[NBF], nodeL[NBF];
  __shared__ float invL[NBF];

  const int t = threadIdx.x;
  const int n0 = blockIdx.x * NBF;
  const int w = t >> 6, l = t & 63;
  const int lr = l & 15, lk = l >> 4;

  if (t < NBF + 1) startL[t] = startA[min(n0 + t, N)];
  for (int idx = t; idx < NBF * 256; idx += 256)
    accumS[(idx >> 8) * LDC + (idx & 255)] = 0.f;
  __syncthreads();
  if (t < NBF) {
    int cn = startL[t + 1] - startL[t];
    invL[t] = cn > 0 ? 1.0f / (float)cn : 0.f;
  }
  const int sBase = startL[0], sEnd = startL[NBF];

  const unsigned short* B1w = w1aP + (size_t)(w * 32) * 512 + (size_t)l * 8;
  short8 bA[4], bB[4];
  f32x4 acc[2][4];
  const f32x4 zero4 = {0.f, 0.f, 0.f, 0.f};

  float biasA[4];
#pragma unroll
  for (int nt = 0; nt < 4; ++nt) biasA[nt] = b1a[w * 64 + nt * 16 + lr];

  // ---------------- edge phase: chunks of 32 CSR slots ----------------
  for (int s = sBase; s < sEnd; s += NBF) {
    __syncthreads();  // prev reduce done reading nodeL/As
    if (t < NBF) {
      int slot = s + t;
      int sl = slot < sEnd ? slot : sEnd - 1;
      int e = eid[sl];
      eidL[t] = e;
      rowiL[t] = row_idx[e];
      int lo = 0;  // largest n in [0,31] with startL[n] <= sl (binary lifting)
#pragma unroll
      for (int st = 16; st > 0; st >>= 1)
        if (lo + st <= NBF - 1 && startL[lo + st] <= sl) lo += st;
      nodeL[t] = lo;
    }
#pragma unroll
    for (int n = 0; n < 4; ++n) bA[n] = *(const short8*)(B1w + n * 4096);
    __syncthreads();

    // stage: [32 slots][256 bf16] = (xH[row] | f2bf(eattr[e]))
    for (int idx = t; idx < NBF * 32; idx += 256) {
      int r = idx >> 5, g = idx & 31;
      us8 v;
      if (g < 16) {
        v = *(const us8*)(xH + (size_t)rowiL[r] * 128 + g * 8);
      } else {
        const fvec4* src = (const fvec4*)(eattr + (size_t)eidL[r] * 128 + (size_t)(g - 16) * 8);
        fvec4 a = __builtin_nontemporal_load(src);
        fvec4 b = __builtin_nontemporal_load(src + 1);
        v[0] = f2bf(a.x); v[1] = f2bf(a.y); v[2] = f2bf(a.z); v[3] = f2bf(a.w);
        v[4] = f2bf(b.x); v[5] = f2bf(b.y); v[6] = f2bf(b.z); v[7] = f2bf(b.w);
      }
      *(us8*)(&As[r * LDA + g * 8]) = v;
    }
    __syncthreads();

    // GEMM1: [32,256] x W1a[256,256], B double-buffered
#pragma unroll
    for (int mt = 0; mt < 2; ++mt)
#pragma unroll
      for (int nt = 0; nt < 4; ++nt) acc[mt][nt] = zero4;
#pragma unroll
    for (int kt = 0; kt < 8; ++kt) {
      short8* bc = (kt & 1) ? bB : bA;
      short8* bn = (kt & 1) ? bA : bB;
      if (kt < 7) {
#pragma unroll
        for (int n = 0; n < 4; ++n) bn[n] = *(const short8*)(B1w + n * 4096 + (kt + 1) * 512);
      }
      short8 a[2];
#pragma unroll
      for (int mt = 0; mt < 2; ++mt)
        a[mt] = *(const short8*)(&As[(mt * 16 + lr) * LDA + kt * 32 + lk * 8]);
#pragma unroll
      for (int mt = 0; mt < 2; ++mt)
#pragma unroll
        for (int nt = 0; nt < 4; ++nt)
          acc[mt][nt] = __builtin_amdgcn_mfma_f32_16x16x32_bf16(a[mt], bc[nt], acc[mt][nt], 0, 0, 0);
    }
    __syncthreads();  // all As reads done

    // epilogue: bias + ELU -> bf16 back into As
#pragma unroll
    for (int nt = 0; nt < 4; ++nt) {
      int col = w * 64 + nt * 16 + lr;
#pragma unroll
      for (int mt = 0; mt < 2; ++mt)
#pragma unroll
        for (int j = 0; j < 4; ++j) {
          float v = elu_f(acc[mt][nt][j] + biasA[nt]);
          As[(mt * 16 + lk * 4 + j) * LDA + col] = f2bf(v);
        }
    }
    __syncthreads();

    // segmented reduce into block-local accum; thread t owns column t.
    {
      int c = sEnd - s; if (c > NBF) c = NBF;
      const int col = t;
      float run = 0.f;
      int prev = nodeL[0];
      for (int r = 0; r < c; ++r) {
        int nd = nodeL[r];
        if (nd != prev) { accumS[prev * LDC + col] += run; run = 0.f; prev = nd; }
        run += bf2f(As[r * LDA + col]);
      }
      accumS[prev * LDC + col] += run;
    }
  }
  __syncthreads();

  // ---------------- node phase ----------------
  const unsigned short* B0  = w1bP + (size_t)(w * 32) * 512 + (size_t)l * 8;
  const unsigned short* B1n = w2aP + (size_t)(w * 48) * 512 + (size_t)l * 8;
  const unsigned short* B2n = w2bP + (size_t)(w * 16) * 512 + (size_t)l * 8;

#pragma unroll
  for (int n = 0; n < 4; ++n) bA[n] = *(const short8*)(B0 + n * 4096);

  // magg -> As (stride LDA) = accum * inv, bf16
  for (int idx = t; idx < NBF * 64; idx += 256) {
    int nn = idx >> 6, c4 = idx & 63;
    float inv = invL[nn];
    const float* a = &accumS[nn * LDC + c4 * 4];
    us4 o;
    o.x = f2bf(a[0] * inv); o.y = f2bf(a[1] * inv);
    o.z = f2bf(a[2] * inv); o.w = f2bf(a[3] * inv);
    *(us4*)(&As[nn * LDA + c4 * 4]) = o;
  }
  __syncthreads();  // magg staged; accum reads done -> free to alias as XB

  // GEMM-u: magg[32,256] x W1b[256,256]
  f32x4 accU[2][4];
#pragma unroll
  for (int mt = 0; mt < 2; ++mt)
#pragma unroll
    for (int nt = 0; nt < 4; ++nt) accU[mt][nt] = zero4;
#pragma unroll
  for (int kt = 0; kt < 8; ++kt) {
    short8* bc = (kt & 1) ? bB : bA;
    short8* bn = (kt & 1) ? bA : bB;
    if (kt < 7) {
#pragma unroll
      for (int n = 0; n < 4; ++n) bn[n] = *(const short8*)(B0 + n * 4096 + (kt + 1) * 512);
    }
    short8 a[2];
#pragma unroll
    for (int mt = 0; mt < 2; ++mt)
      a[mt] = *(const short8*)(&As[(mt * 16 + lr) * LDA + kt * 32 + lk * 8]);
#pragma unroll
    for (int mt = 0; mt < 2; ++mt)
#pragma unroll
      for (int nt = 0; nt < 4; ++nt)
        accU[mt][nt] = __builtin_amdgcn_mfma_f32_16x16x32_bf16(a[mt], bc[nt], accU[mt][nt], 0, 0, 0);
  }

  unsigned short* XB = (unsigned short*)accumS;  // [32][392] bf16, aliases accum

  // stage x part into XB cols [0,128)
  for (int idx = t; idx < NBF * 16; idx += 256) {
    int nn = idx >> 4, g = idx & 15;
    int node = n0 + nn;
    us8 v = {0, 0, 0, 0, 0, 0, 0, 0};
    if (node < N) v = *(const us8*)(xH + (size_t)node * 128 + g * 8);
    *(us8*)(&XB[nn * LDX + g * 8]) = v;
  }

  // prefetch W2a kt=0
#pragma unroll
  for (int n = 0; n < 4; ++n) bA[n] = *(const short8*)(B1n + n * 6144);

  // u = accU + gated b1b -> XB cols [128,384)
#pragma unroll
  for (int nt = 0; nt < 4; ++nt) {
    int col = w * 64 + nt * 16 + lr;
    float bias = b1b[col];
#pragma unroll
    for (int mt = 0; mt < 2; ++mt)
#pragma unroll
      for (int j = 0; j < 4; ++j) {
        int row = mt * 16 + lk * 4 + j;
        float g = invL[row] > 0.f ? 1.f : 0.f;
        XB[row * LDX + 128 + col] = f2bf(accU[mt][nt][j] + g * bias);
      }
  }
  __syncthreads();  // XB fully staged; As GEMM-u reads done

  // MLP2 GEMM1: [32,384] x W2a[384,256]
#pragma unroll
  for (int mt = 0; mt < 2; ++mt)
#pragma unroll
    for (int nt = 0; nt < 4; ++nt) acc[mt][nt] = zero4;
#pragma unroll
  for (int kt = 0; kt < 12; ++kt) {
    short8* bc = (kt & 1) ? bB : bA;
    short8* bn = (kt & 1) ? bA : bB;
    if (kt < 11) {
#pragma unroll
      for (int n = 0; n < 4; ++n) bn[n] = *(const short8*)(B1n + n * 6144 + (kt + 1) * 512);
    }
    short8 a[2];
#pragma unroll
    for (int mt = 0; mt < 2; ++mt)
      a[mt] = *(const short8*)(&XB[(mt * 16 + lr) * LDX + kt * 32 + lk * 8]);
#pragma unroll
    for (int mt = 0; mt < 2; ++mt)
#pragma unroll
      for (int nt = 0; nt < 4; ++nt)
        acc[mt][nt] = __builtin_amdgcn_mfma_f32_16x16x32_bf16(a[mt], bc[nt], acc[mt][nt], 0, 0, 0);
  }

#pragma unroll
  for (int n = 0; n < 2; ++n) bA[n] = *(const short8*)(B2n + n * 4096);

  __syncthreads();

  // epilogue: bias + ELU -> H into As (stride LDA)
#pragma unroll
  for (int nt = 0; nt < 4; ++nt) {
    int col = w * 64 + nt * 16 + lr;
    float bias = b2a[col];
#pragma unroll
    for (int mt = 0; mt < 2; ++mt)
#pragma unroll
      for (int j = 0; j < 4; ++j) {
        float v = elu_f(acc[mt][nt][j] + bias);
        As[(mt * 16 + lk * 4 + j) * LDA + col] = f2bf(v);
      }
  }
  __syncthreads();

  // GEMM2: H[32,256] x W2b[256,128]; wave w owns cols [32w, 32w+32)
  f32x4 acc2[2][2];
#pragma unroll
  for (int mt = 0; mt < 2; ++mt)
#pragma unroll
    for (int nt = 0; nt < 2; ++nt) acc2[mt][nt] = zero4;
#pragma unroll
  for (int kt = 0; kt < 8; ++kt) {
    short8* bc = (kt & 1) ? bB : bA;
    short8* bn = (kt & 1) ? bA : bB;
    if (kt < 7) {
#pragma unroll
      for (int n = 0; n < 2; ++n) bn[n] = *(const short8*)(B2n + n * 4096 + (kt + 1) * 512);
    }
    short8 a[2];
#pragma unroll
    for (int mt = 0; mt < 2; ++mt)
      a[mt] = *(const short8*)(&As[(mt * 16 + lr) * LDA + kt * 32 + lk * 8]);
#pragma unroll
    for (int mt = 0; mt < 2; ++mt)
#pragma unroll
      for (int nt = 0; nt < 2; ++nt)
        acc2[mt][nt] = __builtin_amdgcn_mfma_f32_16x16x32_bf16(a[mt], bc[nt], acc2[mt][nt], 0, 0, 0);
  }

  // store out
#pragma unroll
  for (int nt = 0; nt < 2; ++nt) {
    int col = w * 32 + nt * 16 + lr;
    float bias = b2b[col];
#pragma unroll
    for (int mt = 0; mt < 2; ++mt)
#pragma unroll
      for (int j = 0; j < 4; ++j) {
        int node = n0 + mt * 16 + lk * 4 + j;
        if (node < N) out[(size_t)node * 128 + col] = acc2[mt][nt][j] + bias;
      }
  }
}

extern "C" void kernel_launch(void* const* d_in, const int* in_sizes, int n_in,
                              void* d_out, int out_size, void* d_ws, size_t ws_size,
                              hipStream_t stream) {
  const float* x = (const float*)d_in[0];
  const int* ei = (const int*)d_in[1];
  const float* eattr = (const float*)d_in[2];
  const float* W1a = (const float*)d_in[5];
  const float* b1a = (const float*)d_in[6];
  const float* W1b = (const float*)d_in[7];
  const float* b1b = (const float*)d_in[8];
  const float* W2a = (const float*)d_in[9];
  const float* b2a = (const float*)d_in[10];
  const float* W2b = (const float*)d_in[11];
  const float* b2b = (const float*)d_in[12];

  const int N = in_sizes[0] / 128;   // 25000
  const int E = in_sizes[2] / 128;   // 400000

  char* ws = (char*)d_ws;
  size_t off = 0;
  int* cntbuf = (int*)(ws + off); off += (size_t)N * 4;
  int* startA = (int*)(ws + off); off += (size_t)(N + 1) * 4;
  int* offs   = (int*)(ws + off); off += (size_t)N * 4;
  int* eid    = (int*)(ws + off); off += (size_t)E * 4;
  off = (off + 255) & ~(size_t)255;
  unsigned short* xH   = (unsigned short*)(ws + off); off += (size_t)N * 128 * 2;
  unsigned short* w1aP = (unsigned short*)(ws + off); off += 256 * 256 * 2;
  unsigned short* w1bP = (unsigned short*)(ws + off); off += 256 * 256 * 2;
  unsigned short* w2aP = (unsigned short*)(ws + off); off += 384 * 256 * 2;
  unsigned short* w2bP = (unsigned short*)(ws + off);

  (void)hipMemsetAsync(cntbuf, 0, (size_t)N * 4, stream);

  const int hb = (E + 255) / 256;                  // hist blocks
  const int xElems = N * 128;
  const int xb = (xElems / 8 + 255) / 256;         // x-convert blocks

  prep_kernel<<<1024 + hb + xb, 256, 0, stream>>>(
      W1a, W1b, W2a, W2b, w1aP, w1bP, w2aP, w2bP, ei + E, cntbuf, E, hb, x, xH, xElems);

  scan_kernel<<<1, 1024, 0, stream>>>(cntbuf, startA, offs, N, E);
  eid_kernel<<<hb, 256, 0, stream>>>(ei + E, offs, eid, E);

  fused_kernel<<<(N + NBF - 1) / NBF, 256, 0, stream>>>(
      xH, eid, ei, eattr, startA, b1a, b1b, b2a, b2b,
      w1aP, w1bP, w2aP, w2bP, (float*)d_out, N);
}

// Round 16
// 327.812 us; speedup vs baseline: 1.3807x; 1.3807x over previous
//
#include <hip/hip_runtime.h>
#include <hip/hip_bf16.h>
#include <stdint.h>

typedef short short8 __attribute__((ext_vector_type(8)));
typedef float f32x4 __attribute__((ext_vector_type(4)));
typedef float fvec4 __attribute__((ext_vector_type(4)));
typedef unsigned short us4 __attribute__((ext_vector_type(4)));
typedef unsigned short us8 __attribute__((ext_vector_type(8)));

// native float->bf16 (RNE)
static __device__ __forceinline__ unsigned short f2bf(float f) {
  return __bfloat16_as_ushort(__float2bfloat16(f));
}

static __device__ __forceinline__ float bf2f(unsigned short u) {
  union { uint32_t u; float f; } v; v.u = (uint32_t)u << 16;
  return v.f;
}

// fast ELU: __expf -> v_exp_f32. |err| ~1e-7, fine vs 2e-2 threshold.
static __device__ __forceinline__ float elu_f(float v) {
  return v > 0.0f ? v : __expf(v) - 1.0f;
}

// Fused prep, three concurrent block ranges:
//   [0, 1024)             : pack all 4 weights into MFMA B-fragment order
//   [1024, 1024+hb)       : histogram dst counts
//   [1024+hb, ...)        : convert x (f32) -> xH (bf16)
__global__ void prep_kernel(const float* __restrict__ W1a, const float* __restrict__ W1b,
                            const float* __restrict__ W2a, const float* __restrict__ W2b,
                            unsigned short* __restrict__ w1aP, unsigned short* __restrict__ w1bP,
                            unsigned short* __restrict__ w2aP, unsigned short* __restrict__ w2bP,
                            const int* __restrict__ col_idx, int* __restrict__ cnt, int E,
                            int hb, const float* __restrict__ x,
                            unsigned short* __restrict__ xH, int xElems,
                            float* __restrict__ agg, int aggN) {
  int b = blockIdx.x;
  if (b < 1024) {
    int p = b * 256 + threadIdx.x;
    const float* W; unsigned short* dst; int KT, Nc, q;
    if (p < 65536)       { W = W1a; dst = w1aP; KT = 8;  Nc = 256; q = p; }
    else if (p < 131072) { W = W1b; dst = w1bP; KT = 8;  Nc = 256; q = p - 65536; }
    else if (p < 229376) { W = W2a; dst = w2aP; KT = 12; Nc = 256; q = p - 131072; }
    else                 { W = W2b; dst = w2bP; KT = 8;  Nc = 128; q = p - 229376; }
    int i = q & 7;
    int l = (q >> 3) & 63;
    int rest = q >> 9;
    int kt = rest % KT;
    int nt = rest / KT;
    dst[q] = f2bf(W[(size_t)(kt * 32 + (l >> 4) * 8 + i) * Nc + nt * 16 + (l & 15)]);
  } else if (b < 1024 + hb) {
    int i = (b - 1024) * 256 + threadIdx.x;
    if (i < E) atomicAdd(&cnt[col_idx[i]], 1);
  } else {
    int idx = (b - 1024 - hb) * 256 + threadIdx.x;  // 8-float chunk index
    if (idx * 8 < xElems) {
      const float* src = x + (size_t)idx * 8;
      fvec4 a = *(const fvec4*)src;
      fvec4 c = *(const fvec4*)(src + 4);
      us8 o;
      o[0] = f2bf(a.x); o[1] = f2bf(a.y); o[2] = f2bf(a.z); o[3] = f2bf(a.w);
      o[4] = f2bf(c.x); o[5] = f2bf(c.y); o[6] = f2bf(c.z); o[7] = f2bf(c.w);
      *(us8*)(xH + (size_t)idx * 8) = o;
    }
    // this range also zeroes agg (disjoint index space)
    if (idx * 4 < aggN) {
      fvec4 z = {0.f, 0.f, 0.f, 0.f};
      *(fvec4*)(agg + (size_t)idx * 4) = z;
    }
  }
}

// single-launch scan: each thread serially owns a chunk, one 1024-wide block scan.
__global__ __launch_bounds__(1024) void scan_kernel(const int* __restrict__ cnt,
                                                    int* __restrict__ startA,
                                                    int* __restrict__ offs, int N, int E) {
  __shared__ int partial[1024];
  const int t = threadIdx.x;
  const int chunk = (N + 1023) >> 10;
  const int base = t * chunk;
  int s = 0;
  for (int i = 0; i < chunk; ++i) {
    int idx = base + i;
    if (idx < N) s += cnt[idx];
  }
  partial[t] = s;
  __syncthreads();
  for (int o = 1; o < 1024; o <<= 1) {
    int a = (t >= o) ? partial[t - o] : 0;
    __syncthreads();
    partial[t] += a;
    __syncthreads();
  }
  int run = partial[t] - s;
  for (int i = 0; i < chunk; ++i) {
    int idx = base + i;
    if (idx < N) {
      startA[idx] = run;
      offs[idx] = run;
      run += cnt[idx];
    }
  }
  if (t == 0) startA[N] = E;
}

// dst-sorted edge list: eid[csr_slot] = edge
__global__ void eid_kernel(const int* __restrict__ col_idx, int* __restrict__ offs,
                           int* __restrict__ eid, int E) {
  int i = blockIdx.x * blockDim.x + threadIdx.x;
  if (i < E) eid[atomicAdd(&offs[col_idx[i]], 1)] = i;
}

#define LDA 264  // 256 + 8 pad (bf16 elems); 528B row stride, 16B aligned
#define EBR 32   // CSR slots per block

// 32 dst-sorted CSR slots/block, 4 waves; wave w owns output cols [64w,64w+64),
// acc[2][4]. STAGING RESTRUCTURED vs R13: thread t owns row t>>3, chunks
// (t&7)*4..+3; reads its own eid (8 threads/row -> L2 broadcast), then issues
// ALL its independent global loads back-to-back into registers before any LDS
// write -- 4-8 outstanding DRAM misses/thread instead of ~1 (the R13 staging
// loop serialized load->convert->ds_write per iteration). One barrier removed.
// GEMM1 + ELU + segmented reduce (W1b applied post-mean in node kernel).
__global__ __launch_bounds__(256, 6) void edge_mlp_kernel(
    const unsigned short* __restrict__ xH, const int* __restrict__ row_idx,
    const int* __restrict__ col_idx, const float* __restrict__ eattr,
    const float* __restrict__ b1a, const unsigned short* __restrict__ w1aP,
    const int* __restrict__ eid, float* __restrict__ agg) {
  __shared__ __align__(16) unsigned short As[EBR * LDA];
  __shared__ int dsts[EBR];
  const int t = threadIdx.x;
  const int e0 = blockIdx.x * EBR;

  const int r = t >> 3;          // row 0..31
  const int g0 = (t & 7) << 2;   // first us8-chunk of 4 owned by this thread

  // per-thread direct index reads (8 threads/row hit the same address -> L2)
  int e = eid[e0 + r];

  // issue ALL independent global loads immediately
  us8 v[4];
  if (g0 < 16) {
    int row = row_idx[e];
    const us8* src = (const us8*)(xH + (size_t)row * 128 + (size_t)g0 * 8);
#pragma unroll
    for (int i = 0; i < 4; ++i) v[i] = src[i];
  } else {
    const fvec4* src = (const fvec4*)(eattr + (size_t)e * 128 + (size_t)(g0 - 16) * 8);
#pragma unroll
    for (int i = 0; i < 4; ++i) {
      fvec4 a = __builtin_nontemporal_load(src + 2 * i);
      fvec4 b = __builtin_nontemporal_load(src + 2 * i + 1);
      v[i][0] = f2bf(a.x); v[i][1] = f2bf(a.y); v[i][2] = f2bf(a.z); v[i][3] = f2bf(a.w);
      v[i][4] = f2bf(b.x); v[i][5] = f2bf(b.y); v[i][6] = f2bf(b.z); v[i][7] = f2bf(b.w);
    }
  }
  if ((t & 7) == 0) dsts[r] = col_idx[e];

  const int w = t >> 6, l = t & 63;
  const int lr = l & 15, lk = l >> 4;
  const unsigned short* B1 = w1aP + (size_t)(w * 32) * 512 + (size_t)l * 8;

  short8 bA[4], bB[4];
#pragma unroll
  for (int n = 0; n < 4; ++n) bA[n] = *(const short8*)(B1 + n * 4096);

  // write staged rows to LDS
#pragma unroll
  for (int i = 0; i < 4; ++i)
    *(us8*)(&As[r * LDA + (g0 + i) * 8]) = v[i];
  __syncthreads();

  f32x4 acc[2][4];
  const f32x4 zero4 = {0.f, 0.f, 0.f, 0.f};
#pragma unroll
  for (int mt = 0; mt < 2; ++mt)
#pragma unroll
    for (int nt = 0; nt < 4; ++nt) acc[mt][nt] = zero4;

  // GEMM1: [32,256] x W1a[256,256], B double-buffered
#pragma unroll
  for (int kt = 0; kt < 8; ++kt) {
    short8* bc = (kt & 1) ? bB : bA;
    short8* bn = (kt & 1) ? bA : bB;
    if (kt < 7) {
#pragma unroll
      for (int n = 0; n < 4; ++n) bn[n] = *(const short8*)(B1 + n * 4096 + (kt + 1) * 512);
    }
    short8 a[2];
#pragma unroll
    for (int mt = 0; mt < 2; ++mt)
      a[mt] = *(const short8*)(&As[(mt * 16 + lr) * LDA + kt * 32 + lk * 8]);
#pragma unroll
    for (int mt = 0; mt < 2; ++mt)
#pragma unroll
      for (int nt = 0; nt < 4; ++nt)
        acc[mt][nt] = __builtin_amdgcn_mfma_f32_16x16x32_bf16(a[mt], bc[nt], acc[mt][nt], 0, 0, 0);
  }
  __syncthreads();  // all waves done reading As

  // epilogue: bias + ELU -> bf16 back into As
#pragma unroll
  for (int nt = 0; nt < 4; ++nt) {
    int col = w * 64 + nt * 16 + lr;
    float bias = b1a[col];
#pragma unroll
    for (int mt = 0; mt < 2; ++mt)
#pragma unroll
      for (int j = 0; j < 4; ++j) {
        float vv = elu_f(acc[mt][nt][j] + bias);
        As[(mt * 16 + lk * 4 + j) * LDA + col] = f2bf(vv);
      }
  }
  __syncthreads();

  // segmented reduction over dst-runs; thread t owns column t.
  {
    const int col = t;
    float run = 0.f;
    int prev = dsts[0];
    int segstart = 0;
#pragma unroll 8
    for (int rr = 0; rr < EBR; ++rr) {
      int d = dsts[rr];
      if (d != prev) {
        if (segstart == 0)
          atomicAdd(&agg[(size_t)prev * 256 + col], run);
        else
          agg[(size_t)prev * 256 + col] = run;  // interior: sole owner
        run = 0.f;
        prev = d;
        segstart = rr;
      }
      run += bf2f(As[rr * LDA + col]);
    }
    atomicAdd(&agg[(size_t)prev * 256 + col], run);  // tail touches tile edge
  }
}

#define LDN 392  // 384 + 8 pad

// 64 nodes/block, 4 waves. [proven: unchanged since R10]
__global__ __launch_bounds__(256, 3) void node_mlp_kernel(
    const float* __restrict__ x, const float* __restrict__ agg,
    const int* __restrict__ startA, const float* __restrict__ b1b,
    const float* __restrict__ b2a, const float* __restrict__ b2b,
    const unsigned short* __restrict__ w1bP, const unsigned short* __restrict__ w2aP,
    const unsigned short* __restrict__ w2bP,
    float* __restrict__ out, int N) {
  __shared__ __align__(16) unsigned short As[64 * LDN];
  __shared__ float inv64[64];
  const int t = threadIdx.x;
  const int n0 = blockIdx.x * 64;

  const int w = t >> 6, l = t & 63;
  const int lr = l & 15, lk = l >> 4;
  const unsigned short* B0 = w1bP + (size_t)(w * 32) * 512 + (size_t)l * 8;
  const unsigned short* B1 = w2aP + (size_t)(w * 48) * 512 + (size_t)l * 8;
  const unsigned short* B2 = w2bP + (size_t)(w * 16) * 512 + (size_t)l * 8;

  if (t < 64) {
    int node = n0 + t;
    int cn = (node < N) ? (startA[node + 1] - startA[node]) : 0;
    inv64[t] = cn > 0 ? 1.0f / (float)cn : 0.f;
  }

  short8 bA[4], bB[4];
#pragma unroll
  for (int n = 0; n < 4; ++n) bA[n] = *(const short8*)(B0 + n * 4096);

  __syncthreads();  // inv64 ready

  // stage magg: [64][264] bf16 = agg[node]*inv
  for (int idx = t; idx < 64 * 64; idx += 256) {
    int nn = idx >> 6, c4 = idx & 63;
    int node = n0 + nn;
    fvec4 v = {0.f, 0.f, 0.f, 0.f};
    if (node < N) {
      float inv = inv64[nn];
      fvec4 a = *(const fvec4*)(agg + (size_t)node * 256 + c4 * 4);
      v.x = a.x * inv; v.y = a.y * inv; v.z = a.z * inv; v.w = a.w * inv;
    }
    us4 o;
    o.x = f2bf(v.x); o.y = f2bf(v.y); o.z = f2bf(v.z); o.w = f2bf(v.w);
    *(us4*)(&As[nn * 264 + c4 * 4]) = o;
  }
  __syncthreads();

  const f32x4 zero4 = {0.f, 0.f, 0.f, 0.f};
  f32x4 accU[4][4];
#pragma unroll
  for (int mt = 0; mt < 4; ++mt)
#pragma unroll
    for (int nt = 0; nt < 4; ++nt) accU[mt][nt] = zero4;

  // GEMM-u: magg[64,256] x W1b[256,256]
#pragma unroll
  for (int kt = 0; kt < 8; ++kt) {
    short8* bc = (kt & 1) ? bB : bA;
    short8* bn = (kt & 1) ? bA : bB;
    if (kt < 7) {
#pragma unroll
      for (int n = 0; n < 4; ++n) bn[n] = *(const short8*)(B0 + n * 4096 + (kt + 1) * 512);
    }
    short8 a[4];
#pragma unroll
    for (int mt = 0; mt < 4; ++mt)
      a[mt] = *(const short8*)(&As[(mt * 16 + lr) * 264 + kt * 32 + lk * 8]);
#pragma unroll
    for (int mt = 0; mt < 4; ++mt)
#pragma unroll
      for (int nt = 0; nt < 4; ++nt)
        accU[mt][nt] = __builtin_amdgcn_mfma_f32_16x16x32_bf16(a[mt], bc[nt], accU[mt][nt], 0, 0, 0);
  }

  // prefetch W2a kt=0
#pragma unroll
  for (int n = 0; n < 4; ++n) bA[n] = *(const short8*)(B1 + n * 6144);

  __syncthreads();  // magg reads done; As re-purposed at stride 392

  // stage x into cols [0,128) of the [64][392] buffer
  for (int idx = t; idx < 64 * 32; idx += 256) {
    int nn = idx >> 5, c4 = idx & 31;
    int node = n0 + nn;
    fvec4 v = {0.f, 0.f, 0.f, 0.f};
    if (node < N) v = *(const fvec4*)(x + (size_t)node * 128 + c4 * 4);
    us4 o;
    o.x = f2bf(v.x); o.y = f2bf(v.y); o.z = f2bf(v.z); o.w = f2bf(v.w);
    *(us4*)(&As[nn * LDN + c4 * 4]) = o;
  }

  // write u = accU + b1b (gated by cnt>0) into cols [128,384)
#pragma unroll
  for (int nt = 0; nt < 4; ++nt) {
    int col = w * 64 + nt * 16 + lr;
    float bias = b1b[col];
#pragma unroll
    for (int mt = 0; mt < 4; ++mt)
#pragma unroll
      for (int j = 0; j < 4; ++j) {
        int row = mt * 16 + lk * 4 + j;
        float g = inv64[row] > 0.f ? 1.f : 0.f;
        As[row * LDN + 128 + col] = f2bf(accU[mt][nt][j] + g * bias);
      }
  }
  __syncthreads();

  f32x4 acc[4][4];
#pragma unroll
  for (int mt = 0; mt < 4; ++mt)
#pragma unroll
    for (int nt = 0; nt < 4; ++nt) acc[mt][nt] = zero4;

  // MLP2 GEMM1: [64,384] x W2a[384,256]
#pragma unroll
  for (int kt = 0; kt < 12; ++kt) {
    short8* bc = (kt & 1) ? bB : bA;
    short8* bn = (kt & 1) ? bA : bB;
    if (kt < 11) {
#pragma unroll
      for (int n = 0; n < 4; ++n) bn[n] = *(const short8*)(B1 + n * 6144 + (kt + 1) * 512);
    }
    short8 a[4];
#pragma unroll
    for (int mt = 0; mt < 4; ++mt)
      a[mt] = *(const short8*)(&As[(mt * 16 + lr) * LDN + kt * 32 + lk * 8]);
#pragma unroll
    for (int mt = 0; mt < 4; ++mt)
#pragma unroll
      for (int nt = 0; nt < 4; ++nt)
        acc[mt][nt] = __builtin_amdgcn_mfma_f32_16x16x32_bf16(a[mt], bc[nt], acc[mt][nt], 0, 0, 0);
  }

#pragma unroll
  for (int n = 0; n < 2; ++n) bA[n] = *(const short8*)(B2 + n * 4096);

  __syncthreads();

  // epilogue1: bias + ELU -> H (reuse As, stride 264)
#pragma unroll
  for (int nt = 0; nt < 4; ++nt) {
    int col = w * 64 + nt * 16 + lr;
    float bias = b2a[col];
#pragma unroll
    for (int mt = 0; mt < 4; ++mt)
#pragma unroll
      for (int j = 0; j < 4; ++j) {
        float v = elu_f(acc[mt][nt][j] + bias);
        As[(mt * 16 + lk * 4 + j) * 264 + col] = f2bf(v);
      }
  }
  __syncthreads();

  // GEMM2: H[64,256] x W2b[256,128]; wave w owns cols [32w, 32w+32)
  f32x4 acc2[4][2];
#pragma unroll
  for (int mt = 0; mt < 4; ++mt)
#pragma unroll
    for (int nt = 0; nt < 2; ++nt) acc2[mt][nt] = zero4;
#pragma unroll
  for (int kt = 0; kt < 8; ++kt) {
    short8* bc = (kt & 1) ? bB : bA;
    short8* bn = (kt & 1) ? bA : bB;
    if (kt < 7) {
#pragma unroll
      for (int n = 0; n < 2; ++n) bn[n] = *(const short8*)(B2 + n * 4096 + (kt + 1) * 512);
    }
    short8 a[4];
#pragma unroll
    for (int mt = 0; mt < 4; ++mt)
      a[mt] = *(const short8*)(&As[(mt * 16 + lr) * 264 + kt * 32 + lk * 8]);
#pragma unroll
    for (int mt = 0; mt < 4; ++mt)
#pragma unroll
      for (int nt = 0; nt < 2; ++nt)
        acc2[mt][nt] = __builtin_amdgcn_mfma_f32_16x16x32_bf16(a[mt], bc[nt], acc2[mt][nt], 0, 0, 0);
  }

  // epilogue2: bias + store
#pragma unroll
  for (int nt = 0; nt < 2; ++nt) {
    int col = w * 32 + nt * 16 + lr;
    float bias = b2b[col];
#pragma unroll
    for (int mt = 0; mt < 4; ++mt)
#pragma unroll
      for (int j = 0; j < 4; ++j) {
        int node = n0 + mt * 16 + lk * 4 + j;
        if (node < N) out[(size_t)node * 128 + col] = acc2[mt][nt][j] + bias;
      }
  }
}

extern "C" void kernel_launch(void* const* d_in, const int* in_sizes, int n_in,
                              void* d_out, int out_size, void* d_ws, size_t ws_size,
                              hipStream_t stream) {
  const float* x = (const float*)d_in[0];
  const int* ei = (const int*)d_in[1];
  const float* eattr = (const float*)d_in[2];
  const float* W1a = (const float*)d_in[5];
  const float* b1a = (const float*)d_in[6];
  const float* W1b = (const float*)d_in[7];
  const float* b1b = (const float*)d_in[8];
  const float* W2a = (const float*)d_in[9];
  const float* b2a = (const float*)d_in[10];
  const float* W2b = (const float*)d_in[11];
  const float* b2b = (const float*)d_in[12];

  const int N = in_sizes[0] / 128;   // 25000
  const int E = in_sizes[2] / 128;   // 400000

  char* ws = (char*)d_ws;
  float* agg = (float*)ws;                              // N*256 f32 (sum of elu(h1))
  size_t off = (size_t)N * 256 * 4;
  int* cntbuf = (int*)(ws + off); off += (size_t)N * 4;
  int* startA = (int*)(ws + off); off += (size_t)(N + 1) * 4;
  int* offs   = (int*)(ws + off); off += (size_t)N * 4;
  int* eid    = (int*)(ws + off); off += (size_t)E * 4;
  off = (off + 255) & ~(size_t)255;
  unsigned short* xH   = (unsigned short*)(ws + off); off += (size_t)N * 128 * 2;
  unsigned short* w1aP = (unsigned short*)(ws + off); off += 256 * 256 * 2;
  unsigned short* w1bP = (unsigned short*)(ws + off); off += 256 * 256 * 2;
  unsigned short* w2aP = (unsigned short*)(ws + off); off += 384 * 256 * 2;
  unsigned short* w2bP = (unsigned short*)(ws + off);

  // zero only cnt via memset (100 KB); agg zero + xH convert run inside prep.
  (void)hipMemsetAsync(cntbuf, 0, (size_t)N * 4, stream);

  const int hb = (E + 255) / 256;                  // hist blocks
  const int xElems = N * 128;
  const int aggN = N * 256;
  // third range covers max(xElems/8, aggN/4) items
  const int tail = (aggN / 4 > xElems / 8) ? aggN / 4 : xElems / 8;
  const int xb = (tail + 255) / 256;

  prep_kernel<<<1024 + hb + xb, 256, 0, stream>>>(
      W1a, W1b, W2a, W2b, w1aP, w1bP, w2aP, w2bP, ei + E, cntbuf, E, hb,
      x, xH, xElems, agg, aggN);

  scan_kernel<<<1, 1024, 0, stream>>>(cntbuf, startA, offs, N, E);
  eid_kernel<<<hb, 256, 0, stream>>>(ei + E, offs, eid, E);

  edge_mlp_kernel<<<E / EBR, 256, 0, stream>>>(xH, ei, ei + E, eattr, b1a, w1aP, eid, agg);

  node_mlp_kernel<<<(N + 63) / 64, 256, 0, stream>>>(x, agg, startA, b1b, b2a, b2b,
                                                     w1bP, w2aP, w2bP, (float*)d_out, N);
}

// Round 17
// 298.130 us; speedup vs baseline: 1.5182x; 1.0996x over previous
//
#include <hip/hip_runtime.h>
#include <hip/hip_bf16.h>
#include <stdint.h>

typedef short short8 __attribute__((ext_vector_type(8)));
typedef float f32x4 __attribute__((ext_vector_type(4)));
typedef float fvec4 __attribute__((ext_vector_type(4)));
typedef unsigned short us4 __attribute__((ext_vector_type(4)));
typedef unsigned short us8 __attribute__((ext_vector_type(8)));

// native float->bf16 (RNE)
static __device__ __forceinline__ unsigned short f2bf(float f) {
  return __bfloat16_as_ushort(__float2bfloat16(f));
}

static __device__ __forceinline__ float bf2f(unsigned short u) {
  union { uint32_t u; float f; } v; v.u = (uint32_t)u << 16;
  return v.f;
}

// fast ELU: __expf -> v_exp_f32. |err| ~1e-7, fine vs 2e-2 threshold.
static __device__ __forceinline__ float elu_f(float v) {
  return v > 0.0f ? v : __expf(v) - 1.0f;
}

// Fused prep, concurrent block ranges:
//   [0, 1024)        : pack all 4 weights into MFMA B-fragment order
//   [1024, 1024+hb)  : histogram dst counts
//   [1024+hb, ...)   : tail range, per-idx guards: zero agg (f32) /
//                      convert x->xH (bf16) / convert eattr->eattrH (bf16, SEQUENTIAL)
__global__ void prep_kernel(const float* __restrict__ W1a, const float* __restrict__ W1b,
                            const float* __restrict__ W2a, const float* __restrict__ W2b,
                            unsigned short* __restrict__ w1aP, unsigned short* __restrict__ w1bP,
                            unsigned short* __restrict__ w2aP, unsigned short* __restrict__ w2bP,
                            const int* __restrict__ col_idx, int* __restrict__ cnt, int E,
                            int hb, const float* __restrict__ x,
                            unsigned short* __restrict__ xH, int xElems,
                            float* __restrict__ agg, int aggN,
                            const float* __restrict__ eattr,
                            unsigned short* __restrict__ eattrH, int eElems) {
  int b = blockIdx.x;
  if (b < 1024) {
    int p = b * 256 + threadIdx.x;
    const float* W; unsigned short* dst; int KT, Nc, q;
    if (p < 65536)       { W = W1a; dst = w1aP; KT = 8;  Nc = 256; q = p; }
    else if (p < 131072) { W = W1b; dst = w1bP; KT = 8;  Nc = 256; q = p - 65536; }
    else if (p < 229376) { W = W2a; dst = w2aP; KT = 12; Nc = 256; q = p - 131072; }
    else                 { W = W2b; dst = w2bP; KT = 8;  Nc = 128; q = p - 229376; }
    int i = q & 7;
    int l = (q >> 3) & 63;
    int rest = q >> 9;
    int kt = rest % KT;
    int nt = rest / KT;
    dst[q] = f2bf(W[(size_t)(kt * 32 + (l >> 4) * 8 + i) * Nc + nt * 16 + (l & 15)]);
  } else if (b < 1024 + hb) {
    int i = (b - 1024) * 256 + threadIdx.x;
    if (i < E) atomicAdd(&cnt[col_idx[i]], 1);
  } else {
    int idx = (b - 1024 - hb) * 256 + threadIdx.x;
    if (idx * 4 < aggN) {
      fvec4 z = {0.f, 0.f, 0.f, 0.f};
      *(fvec4*)(agg + (size_t)idx * 4) = z;
    }
    if (idx * 8 < xElems) {
      const float* src = x + (size_t)idx * 8;
      fvec4 a = *(const fvec4*)src;
      fvec4 c = *(const fvec4*)(src + 4);
      us8 o;
      o[0] = f2bf(a.x); o[1] = f2bf(a.y); o[2] = f2bf(a.z); o[3] = f2bf(a.w);
      o[4] = f2bf(c.x); o[5] = f2bf(c.y); o[6] = f2bf(c.z); o[7] = f2bf(c.w);
      *(us8*)(xH + (size_t)idx * 8) = o;
    }
    if (idx * 8 < eElems) {
      const fvec4* src = (const fvec4*)(eattr + (size_t)idx * 8);
      fvec4 a = __builtin_nontemporal_load(src);
      fvec4 c = __builtin_nontemporal_load(src + 1);
      us8 o;
      o[0] = f2bf(a.x); o[1] = f2bf(a.y); o[2] = f2bf(a.z); o[3] = f2bf(a.w);
      o[4] = f2bf(c.x); o[5] = f2bf(c.y); o[6] = f2bf(c.z); o[7] = f2bf(c.w);
      __builtin_nontemporal_store(o, (us8*)(eattrH + (size_t)idx * 8));
    }
  }
}

// single-launch scan: each thread serially owns a chunk, one 1024-wide block scan.
__global__ __launch_bounds__(1024) void scan_kernel(const int* __restrict__ cnt,
                                                    int* __restrict__ startA,
                                                    int* __restrict__ offs, int N, int E) {
  __shared__ int partial[1024];
  const int t = threadIdx.x;
  const int chunk = (N + 1023) >> 10;
  const int base = t * chunk;
  int s = 0;
  for (int i = 0; i < chunk; ++i) {
    int idx = base + i;
    if (idx < N) s += cnt[idx];
  }
  partial[t] = s;
  __syncthreads();
  for (int o = 1; o < 1024; o <<= 1) {
    int a = (t >= o) ? partial[t - o] : 0;
    __syncthreads();
    partial[t] += a;
    __syncthreads();
  }
  int run = partial[t] - s;
  for (int i = 0; i < chunk; ++i) {
    int idx = base + i;
    if (idx < N) {
      startA[idx] = run;
      offs[idx] = run;
      run += cnt[idx];
    }
  }
  if (t == 0) startA[N] = E;
}

// dst-sorted edge list: eid[csr_slot] = edge
__global__ void eid_kernel(const int* __restrict__ col_idx, int* __restrict__ offs,
                           int* __restrict__ eid, int E) {
  int i = blockIdx.x * blockDim.x + threadIdx.x;
  if (i < E) eid[atomicAdd(&offs[col_idx[i]], 1)] = i;
}

#define LDA 264  // 256 + 8 pad (bf16 elems); 528B row stride, 16B aligned
#define EBR 32   // CSR slots per block

// 32 dst-sorted CSR slots/block, 4 waves (R13's proven shape). All inputs
// pre-converted bf16: random gather is now 256B/row (eattrH) instead of 512B.
// Wave-cooperative staging (32 lanes cover one row contiguously). GEMM1 + ELU
// + segmented reduce (W1b applied post-mean in node kernel).
__global__ __launch_bounds__(256, 6) void edge_mlp_kernel(
    const unsigned short* __restrict__ xH, const int* __restrict__ row_idx,
    const int* __restrict__ col_idx, const unsigned short* __restrict__ eattrH,
    const float* __restrict__ b1a, const unsigned short* __restrict__ w1aP,
    const int* __restrict__ eid, float* __restrict__ agg) {
  __shared__ __align__(16) unsigned short As[EBR * LDA];
  __shared__ int rowi[EBR];
  __shared__ int eidx[EBR];
  __shared__ int dsts[EBR];
  const int t = threadIdx.x;
  const int e0 = blockIdx.x * EBR;

  if (t < EBR) {
    int e = eid[e0 + t];
    eidx[t] = e;
    rowi[t] = row_idx[e];
    dsts[t] = col_idx[e];  // non-decreasing across the tile (CSR order)
  }

  const int w = t >> 6, l = t & 63;
  const int lr = l & 15, lk = l >> 4;
  const unsigned short* B1 = w1aP + (size_t)(w * 32) * 512 + (size_t)l * 8;

  short8 bA[4], bB[4];
#pragma unroll
  for (int n = 0; n < 4; ++n) bA[n] = *(const short8*)(B1 + n * 4096);

  __syncthreads();

  // stage A: [32 rows][32 us8 chunks] = (xH[row] | eattrH[e]); 16 lanes cover
  // one row-half contiguously (256B per 16-lane group) -- full coalescing.
  for (int idx = t; idx < EBR * 32; idx += 256) {
    int r = idx >> 5, g = idx & 31;
    us8 v;
    if (g < 16)
      v = *(const us8*)(xH + (size_t)rowi[r] * 128 + (size_t)g * 8);
    else
      v = __builtin_nontemporal_load(
            (const us8*)(eattrH + (size_t)eidx[r] * 128 + (size_t)(g - 16) * 8));
    *(us8*)(&As[r * LDA + g * 8]) = v;
  }
  __syncthreads();

  f32x4 acc[2][4];
  const f32x4 zero4 = {0.f, 0.f, 0.f, 0.f};
#pragma unroll
  for (int mt = 0; mt < 2; ++mt)
#pragma unroll
    for (int nt = 0; nt < 4; ++nt) acc[mt][nt] = zero4;

  // GEMM1: [32,256] x W1a[256,256], B double-buffered
#pragma unroll
  for (int kt = 0; kt < 8; ++kt) {
    short8* bc = (kt & 1) ? bB : bA;
    short8* bn = (kt & 1) ? bA : bB;
    if (kt < 7) {
#pragma unroll
      for (int n = 0; n < 4; ++n) bn[n] = *(const short8*)(B1 + n * 4096 + (kt + 1) * 512);
    }
    short8 a[2];
#pragma unroll
    for (int mt = 0; mt < 2; ++mt)
      a[mt] = *(const short8*)(&As[(mt * 16 + lr) * LDA + kt * 32 + lk * 8]);
#pragma unroll
    for (int mt = 0; mt < 2; ++mt)
#pragma unroll
      for (int nt = 0; nt < 4; ++nt)
        acc[mt][nt] = __builtin_amdgcn_mfma_f32_16x16x32_bf16(a[mt], bc[nt], acc[mt][nt], 0, 0, 0);
  }
  __syncthreads();  // all waves done reading As

  // epilogue: bias + ELU -> bf16 back into As
#pragma unroll
  for (int nt = 0; nt < 4; ++nt) {
    int col = w * 64 + nt * 16 + lr;
    float bias = b1a[col];
#pragma unroll
    for (int mt = 0; mt < 2; ++mt)
#pragma unroll
      for (int j = 0; j < 4; ++j) {
        float v = elu_f(acc[mt][nt][j] + bias);
        As[(mt * 16 + lk * 4 + j) * LDA + col] = f2bf(v);
      }
  }
  __syncthreads();

  // segmented reduction over dst-runs; thread t owns column t.
  {
    const int col = t;
    float run = 0.f;
    int prev = dsts[0];
    int segstart = 0;
#pragma unroll 8
    for (int r = 0; r < EBR; ++r) {
      int d = dsts[r];
      if (d != prev) {
        if (segstart == 0)
          atomicAdd(&agg[(size_t)prev * 256 + col], run);
        else
          agg[(size_t)prev * 256 + col] = run;  // interior: sole owner
        run = 0.f;
        prev = d;
        segstart = r;
      }
      run += bf2f(As[r * LDA + col]);
    }
    atomicAdd(&agg[(size_t)prev * 256 + col], run);  // tail touches tile edge
  }
}

#define LDN 392  // 384 + 8 pad

// 64 nodes/block, 4 waves. [proven: unchanged since R10]
__global__ __launch_bounds__(256, 3) void node_mlp_kernel(
    const float* __restrict__ x, const float* __restrict__ agg,
    const int* __restrict__ startA, const float* __restrict__ b1b,
    const float* __restrict__ b2a, const float* __restrict__ b2b,
    const unsigned short* __restrict__ w1bP, const unsigned short* __restrict__ w2aP,
    const unsigned short* __restrict__ w2bP,
    float* __restrict__ out, int N) {
  __shared__ __align__(16) unsigned short As[64 * LDN];
  __shared__ float inv64[64];
  const int t = threadIdx.x;
  const int n0 = blockIdx.x * 64;

  const int w = t >> 6, l = t & 63;
  const int lr = l & 15, lk = l >> 4;
  const unsigned short* B0 = w1bP + (size_t)(w * 32) * 512 + (size_t)l * 8;
  const unsigned short* B1 = w2aP + (size_t)(w * 48) * 512 + (size_t)l * 8;
  const unsigned short* B2 = w2bP + (size_t)(w * 16) * 512 + (size_t)l * 8;

  if (t < 64) {
    int node = n0 + t;
    int cn = (node < N) ? (startA[node + 1] - startA[node]) : 0;
    inv64[t] = cn > 0 ? 1.0f / (float)cn : 0.f;
  }

  short8 bA[4], bB[4];
#pragma unroll
  for (int n = 0; n < 4; ++n) bA[n] = *(const short8*)(B0 + n * 4096);

  __syncthreads();  // inv64 ready

  // stage magg: [64][264] bf16 = agg[node]*inv
  for (int idx = t; idx < 64 * 64; idx += 256) {
    int nn = idx >> 6, c4 = idx & 63;
    int node = n0 + nn;
    fvec4 v = {0.f, 0.f, 0.f, 0.f};
    if (node < N) {
      float inv = inv64[nn];
      fvec4 a = *(const fvec4*)(agg + (size_t)node * 256 + c4 * 4);
      v.x = a.x * inv; v.y = a.y * inv; v.z = a.z * inv; v.w = a.w * inv;
    }
    us4 o;
    o.x = f2bf(v.x); o.y = f2bf(v.y); o.z = f2bf(v.z); o.w = f2bf(v.w);
    *(us4*)(&As[nn * 264 + c4 * 4]) = o;
  }
  __syncthreads();

  const f32x4 zero4 = {0.f, 0.f, 0.f, 0.f};
  f32x4 accU[4][4];
#pragma unroll
  for (int mt = 0; mt < 4; ++mt)
#pragma unroll
    for (int nt = 0; nt < 4; ++nt) accU[mt][nt] = zero4;

  // GEMM-u: magg[64,256] x W1b[256,256]
#pragma unroll
  for (int kt = 0; kt < 8; ++kt) {
    short8* bc = (kt & 1) ? bB : bA;
    short8* bn = (kt & 1) ? bA : bB;
    if (kt < 7) {
#pragma unroll
      for (int n = 0; n < 4; ++n) bn[n] = *(const short8*)(B0 + n * 4096 + (kt + 1) * 512);
    }
    short8 a[4];
#pragma unroll
    for (int mt = 0; mt < 4; ++mt)
      a[mt] = *(const short8*)(&As[(mt * 16 + lr) * 264 + kt * 32 + lk * 8]);
#pragma unroll
    for (int mt = 0; mt < 4; ++mt)
#pragma unroll
      for (int nt = 0; nt < 4; ++nt)
        accU[mt][nt] = __builtin_amdgcn_mfma_f32_16x16x32_bf16(a[mt], bc[nt], accU[mt][nt], 0, 0, 0);
  }

  // prefetch W2a kt=0
#pragma unroll
  for (int n = 0; n < 4; ++n) bA[n] = *(const short8*)(B1 + n * 6144);

  __syncthreads();  // magg reads done; As re-purposed at stride 392

  // stage x into cols [0,128) of the [64][392] buffer
  for (int idx = t; idx < 64 * 32; idx += 256) {
    int nn = idx >> 5, c4 = idx & 31;
    int node = n0 + nn;
    fvec4 v = {0.f, 0.f, 0.f, 0.f};
    if (node < N) v = *(const fvec4*)(x + (size_t)node * 128 + c4 * 4);
    us4 o;
    o.x = f2bf(v.x); o.y = f2bf(v.y); o.z = f2bf(v.z); o.w = f2bf(v.w);
    *(us4*)(&As[nn * LDN + c4 * 4]) = o;
  }

  // write u = accU + b1b (gated by cnt>0) into cols [128,384)
#pragma unroll
  for (int nt = 0; nt < 4; ++nt) {
    int col = w * 64 + nt * 16 + lr;
    float bias = b1b[col];
#pragma unroll
    for (int mt = 0; mt < 4; ++mt)
#pragma unroll
      for (int j = 0; j < 4; ++j) {
        int row = mt * 16 + lk * 4 + j;
        float g = inv64[row] > 0.f ? 1.f : 0.f;
        As[row * LDN + 128 + col] = f2bf(accU[mt][nt][j] + g * bias);
      }
  }
  __syncthreads();

  f32x4 acc[4][4];
#pragma unroll
  for (int mt = 0; mt < 4; ++mt)
#pragma unroll
    for (int nt = 0; nt < 4; ++nt) acc[mt][nt] = zero4;

  // MLP2 GEMM1: [64,384] x W2a[384,256]
#pragma unroll
  for (int kt = 0; kt < 12; ++kt) {
    short8* bc = (kt & 1) ? bB : bA;
    short8* bn = (kt & 1) ? bA : bB;
    if (kt < 11) {
#pragma unroll
      for (int n = 0; n < 4; ++n) bn[n] = *(const short8*)(B1 + n * 6144 + (kt + 1) * 512);
    }
    short8 a[4];
#pragma unroll
    for (int mt = 0; mt < 4; ++mt)
      a[mt] = *(const short8*)(&As[(mt * 16 + lr) * LDN + kt * 32 + lk * 8]);
#pragma unroll
    for (int mt = 0; mt < 4; ++mt)
#pragma unroll
      for (int nt = 0; nt < 4; ++nt)
        acc[mt][nt] = __builtin_amdgcn_mfma_f32_16x16x32_bf16(a[mt], bc[nt], acc[mt][nt], 0, 0, 0);
  }

#pragma unroll
  for (int n = 0; n < 2; ++n) bA[n] = *(const short8*)(B2 + n * 4096);

  __syncthreads();

  // epilogue1: bias + ELU -> H (reuse As, stride 264)
#pragma unroll
  for (int nt = 0; nt < 4; ++nt) {
    int col = w * 64 + nt * 16 + lr;
    float bias = b2a[col];
#pragma unroll
    for (int mt = 0; mt < 4; ++mt)
#pragma unroll
      for (int j = 0; j < 4; ++j) {
        float v = elu_f(acc[mt][nt][j] + bias);
        As[(mt * 16 + lk * 4 + j) * 264 + col] = f2bf(v);
      }
  }
  __syncthreads();

  // GEMM2: H[64,256] x W2b[256,128]; wave w owns cols [32w, 32w+32)
  f32x4 acc2[4][2];
#pragma unroll
  for (int mt = 0; mt < 4; ++mt)
#pragma unroll
    for (int nt = 0; nt < 2; ++nt) acc2[mt][nt] = zero4;
#pragma unroll
  for (int kt = 0; kt < 8; ++kt) {
    short8* bc = (kt & 1) ? bB : bA;
    short8* bn = (kt & 1) ? bA : bB;
    if (kt < 7) {
#pragma unroll
      for (int n = 0; n < 2; ++n) bn[n] = *(const short8*)(B2 + n * 4096 + (kt + 1) * 512);
    }
    short8 a[4];
#pragma unroll
    for (int mt = 0; mt < 4; ++mt)
      a[mt] = *(const short8*)(&As[(mt * 16 + lr) * 264 + kt * 32 + lk * 8]);
#pragma unroll
    for (int mt = 0; mt < 4; ++mt)
#pragma unroll
      for (int nt = 0; nt < 2; ++nt)
        acc2[mt][nt] = __builtin_amdgcn_mfma_f32_16x16x32_bf16(a[mt], bc[nt], acc2[mt][nt], 0, 0, 0);
  }

  // epilogue2: bias + store
#pragma unroll
  for (int nt = 0; nt < 2; ++nt) {
    int col = w * 32 + nt * 16 + lr;
    float bias = b2b[col];
#pragma unroll
    for (int mt = 0; mt < 4; ++mt)
#pragma unroll
      for (int j = 0; j < 4; ++j) {
        int node = n0 + mt * 16 + lk * 4 + j;
        if (node < N) out[(size_t)node * 128 + col] = acc2[mt][nt][j] + bias;
      }
  }
}

extern "C" void kernel_launch(void* const* d_in, const int* in_sizes, int n_in,
                              void* d_out, int out_size, void* d_ws, size_t ws_size,
                              hipStream_t stream) {
  const float* x = (const float*)d_in[0];
  const int* ei = (const int*)d_in[1];
  const float* eattr = (const float*)d_in[2];
  const float* W1a = (const float*)d_in[5];
  const float* b1a = (const float*)d_in[6];
  const float* W1b = (const float*)d_in[7];
  const float* b1b = (const float*)d_in[8];
  const float* W2a = (const float*)d_in[9];
  const float* b2a = (const float*)d_in[10];
  const float* W2b = (const float*)d_in[11];
  const float* b2b = (const float*)d_in[12];

  const int N = in_sizes[0] / 128;   // 25000
  const int E = in_sizes[2] / 128;   // 400000

  char* ws = (char*)d_ws;
  float* agg = (float*)ws;                              // N*256 f32 (sum of elu(h1))
  size_t off = (size_t)N * 256 * 4;
  int* cntbuf = (int*)(ws + off); off += (size_t)N * 4;
  int* startA = (int*)(ws + off); off += (size_t)(N + 1) * 4;
  int* offs   = (int*)(ws + off); off += (size_t)N * 4;
  int* eid    = (int*)(ws + off); off += (size_t)E * 4;
  off = (off + 255) & ~(size_t)255;
  unsigned short* xH     = (unsigned short*)(ws + off); off += (size_t)N * 128 * 2;
  off = (off + 255) & ~(size_t)255;
  unsigned short* eattrH = (unsigned short*)(ws + off); off += (size_t)E * 128 * 2;
  unsigned short* w1aP = (unsigned short*)(ws + off); off += 256 * 256 * 2;
  unsigned short* w1bP = (unsigned short*)(ws + off); off += 256 * 256 * 2;
  unsigned short* w2aP = (unsigned short*)(ws + off); off += 384 * 256 * 2;
  unsigned short* w2bP = (unsigned short*)(ws + off);

  // zero only cnt via memset (100 KB); agg zero + conversions run inside prep.
  (void)hipMemsetAsync(cntbuf, 0, (size_t)N * 4, stream);

  const int hb = (E + 255) / 256;                  // hist blocks
  const int xElems = N * 128;
  const int aggN = N * 256;
  const int eElems = E * 128;
  // tail range covers the largest of {agg/4, x/8, eattr/8} item counts
  long tail = eElems / 8;
  if (aggN / 4 > tail) tail = aggN / 4;
  if (xElems / 8 > tail) tail = xElems / 8;
  const int tb = (int)((tail + 255) / 256);

  prep_kernel<<<1024 + hb + tb, 256, 0, stream>>>(
      W1a, W1b, W2a, W2b, w1aP, w1bP, w2aP, w2bP, ei + E, cntbuf, E, hb,
      x, xH, xElems, agg, aggN, eattr, eattrH, eElems);

  scan_kernel<<<1, 1024, 0, stream>>>(cntbuf, startA, offs, N, E);
  eid_kernel<<<hb, 256, 0, stream>>>(ei + E, offs, eid, E);

  edge_mlp_kernel<<<E / EBR, 256, 0, stream>>>(xH, ei, ei + E, eattrH, b1a, w1aP, eid, agg);

  node_mlp_kernel<<<(N + 63) / 64, 256, 0, stream>>>(x, agg, startA, b1b, b2a, b2b,
                                                     w1bP, w2aP, w2bP, (float*)d_out, N);
}

// Round 18
// 264.406 us; speedup vs baseline: 1.7118x; 1.1275x over previous
//
#include <hip/hip_runtime.h>
#include <hip/hip_bf16.h>
#include <stdint.h>

typedef short short8 __attribute__((ext_vector_type(8)));
typedef float f32x4 __attribute__((ext_vector_type(4)));
typedef float fvec4 __attribute__((ext_vector_type(4)));
typedef unsigned short us4 __attribute__((ext_vector_type(4)));
typedef unsigned short us8 __attribute__((ext_vector_type(8)));

// native float->bf16 (RNE)
static __device__ __forceinline__ unsigned short f2bf(float f) {
  return __bfloat16_as_ushort(__float2bfloat16(f));
}

static __device__ __forceinline__ float bf2f(unsigned short u) {
  union { uint32_t u; float f; } v; v.u = (uint32_t)u << 16;
  return v.f;
}

// fast ELU: __expf -> v_exp_f32. |err| ~1e-7, fine vs 2e-2 threshold.
static __device__ __forceinline__ float elu_f(float v) {
  return v > 0.0f ? v : __expf(v) - 1.0f;
}

// Fused prep, three concurrent block ranges:
//   [0, 1024)        : pack all 4 weights into MFMA B-fragment order
//   [1024, 1024+hb)  : histogram dst counts
//   [1024+hb, ...)   : zero agg (N*256 f32) + convert x->xH (bf16, cheap: 12.8MB)
__global__ void prep_kernel(const float* __restrict__ W1a, const float* __restrict__ W1b,
                            const float* __restrict__ W2a, const float* __restrict__ W2b,
                            unsigned short* __restrict__ w1aP, unsigned short* __restrict__ w1bP,
                            unsigned short* __restrict__ w2aP, unsigned short* __restrict__ w2bP,
                            const int* __restrict__ col_idx, int* __restrict__ cnt, int E,
                            int hb, float* __restrict__ agg, int aggN,
                            const float* __restrict__ x, unsigned short* __restrict__ xH,
                            int xElems) {
  int b = blockIdx.x;
  if (b < 1024) {
    int p = b * 256 + threadIdx.x;
    const float* W; unsigned short* dst; int KT, Nc, q;
    if (p < 65536)       { W = W1a; dst = w1aP; KT = 8;  Nc = 256; q = p; }
    else if (p < 131072) { W = W1b; dst = w1bP; KT = 8;  Nc = 256; q = p - 65536; }
    else if (p < 229376) { W = W2a; dst = w2aP; KT = 12; Nc = 256; q = p - 131072; }
    else                 { W = W2b; dst = w2bP; KT = 8;  Nc = 128; q = p - 229376; }
    int i = q & 7;
    int l = (q >> 3) & 63;
    int rest = q >> 9;
    int kt = rest % KT;
    int nt = rest / KT;
    dst[q] = f2bf(W[(size_t)(kt * 32 + (l >> 4) * 8 + i) * Nc + nt * 16 + (l & 15)]);
  } else if (b < 1024 + hb) {
    int i = (b - 1024) * 256 + threadIdx.x;
    if (i < E) atomicAdd(&cnt[col_idx[i]], 1);
  } else {
    int idx = (b - 1024 - hb) * 256 + threadIdx.x;
    if (idx * 4 < aggN) {
      fvec4 z = {0.f, 0.f, 0.f, 0.f};
      *(fvec4*)(agg + (size_t)idx * 4) = z;
    }
    if (idx * 8 < xElems) {
      const float* src = x + (size_t)idx * 8;
      fvec4 a = *(const fvec4*)src;
      fvec4 c = *(const fvec4*)(src + 4);
      us8 o;
      o[0] = f2bf(a.x); o[1] = f2bf(a.y); o[2] = f2bf(a.z); o[3] = f2bf(a.w);
      o[4] = f2bf(c.x); o[5] = f2bf(c.y); o[6] = f2bf(c.z); o[7] = f2bf(c.w);
      *(us8*)(xH + (size_t)idx * 8) = o;
    }
  }
}

// single-launch scan: each thread serially owns a chunk, one 1024-wide block scan.
__global__ __launch_bounds__(1024) void scan_kernel(const int* __restrict__ cnt,
                                                    int* __restrict__ startA,
                                                    int* __restrict__ offs, int N, int E) {
  __shared__ int partial[1024];
  const int t = threadIdx.x;
  const int chunk = (N + 1023) >> 10;
  const int base = t * chunk;
  int s = 0;
  for (int i = 0; i < chunk; ++i) {
    int idx = base + i;
    if (idx < N) s += cnt[idx];
  }
  partial[t] = s;
  __syncthreads();
  for (int o = 1; o < 1024; o <<= 1) {
    int a = (t >= o) ? partial[t - o] : 0;
    __syncthreads();
    partial[t] += a;
    __syncthreads();
  }
  int run = partial[t] - s;
  for (int i = 0; i < chunk; ++i) {
    int idx = base + i;
    if (idx < N) {
      startA[idx] = run;
      offs[idx] = run;
      run += cnt[idx];
    }
  }
  if (t == 0) startA[N] = E;
}

// dst-sorted edge list: eid[csr_slot] = edge
__global__ void eid_kernel(const int* __restrict__ col_idx, int* __restrict__ offs,
                           int* __restrict__ eid, int E) {
  int i = blockIdx.x * blockDim.x + threadIdx.x;
  if (i < E) eid[atomicAdd(&offs[col_idx[i]], 1)] = i;
}

#define LDA 264  // 256 + 8 pad (bf16 elems); 528B row stride, 16B aligned
#define EBR 32   // CSR slots per block

// 32 dst-sorted CSR slots/block, 4 waves (R13's proven shape). x gathered as
// bf16 (xH, 256B/row cache reads, half of R13's f32); eattr random-read f32
// (unchanged: prepass conversion measured as a net loss, R17). GEMM1 + ELU +
// segmented reduce (W1b applied post-mean in node kernel).
__global__ __launch_bounds__(256, 6) void edge_mlp_kernel(
    const unsigned short* __restrict__ xH, const int* __restrict__ row_idx,
    const int* __restrict__ col_idx, const float* __restrict__ eattr,
    const float* __restrict__ b1a, const unsigned short* __restrict__ w1aP,
    const int* __restrict__ eid, float* __restrict__ agg) {
  __shared__ __align__(16) unsigned short As[EBR * LDA];
  __shared__ int rowi[EBR];
  __shared__ int eidx[EBR];
  __shared__ int dsts[EBR];
  const int t = threadIdx.x;
  const int e0 = blockIdx.x * EBR;

  if (t < EBR) {
    int e = eid[e0 + t];
    eidx[t] = e;
    rowi[t] = row_idx[e];
    dsts[t] = col_idx[e];  // non-decreasing across the tile (CSR order)
  }

  const int w = t >> 6, l = t & 63;
  const int lr = l & 15, lk = l >> 4;
  const unsigned short* B1 = w1aP + (size_t)(w * 32) * 512 + (size_t)l * 8;

  short8 bA[4], bB[4];
#pragma unroll
  for (int n = 0; n < 4; ++n) bA[n] = *(const short8*)(B1 + n * 4096);

  __syncthreads();

  // stage x half: [32 rows][16 us8 chunks] from xH (bf16, cache-resident)
  for (int idx = t; idx < EBR * 16; idx += 256) {
    int r = idx >> 4, g = idx & 15;
    us8 v = *(const us8*)(xH + (size_t)rowi[r] * 128 + (size_t)g * 8);
    *(us8*)(&As[r * LDA + g * 8]) = v;
  }
  // stage eattr half: [32 rows][32 fvec4 chunks] f32 -> bf16 (cols 128..255)
  for (int idx = t; idx < EBR * 32; idx += 256) {
    int r = idx >> 5, c4 = idx & 31;
    fvec4 v = __builtin_nontemporal_load(
        (const fvec4*)(eattr + (size_t)eidx[r] * 128 + (size_t)c4 * 4));
    us4 o;
    o.x = f2bf(v.x); o.y = f2bf(v.y); o.z = f2bf(v.z); o.w = f2bf(v.w);
    *(us4*)(&As[r * LDA + 128 + c4 * 4]) = o;
  }
  __syncthreads();

  f32x4 acc[2][4];
  const f32x4 zero4 = {0.f, 0.f, 0.f, 0.f};
#pragma unroll
  for (int mt = 0; mt < 2; ++mt)
#pragma unroll
    for (int nt = 0; nt < 4; ++nt) acc[mt][nt] = zero4;

  // GEMM1: [32,256] x W1a[256,256], B double-buffered
#pragma unroll
  for (int kt = 0; kt < 8; ++kt) {
    short8* bc = (kt & 1) ? bB : bA;
    short8* bn = (kt & 1) ? bA : bB;
    if (kt < 7) {
#pragma unroll
      for (int n = 0; n < 4; ++n) bn[n] = *(const short8*)(B1 + n * 4096 + (kt + 1) * 512);
    }
    short8 a[2];
#pragma unroll
    for (int mt = 0; mt < 2; ++mt)
      a[mt] = *(const short8*)(&As[(mt * 16 + lr) * LDA + kt * 32 + lk * 8]);
#pragma unroll
    for (int mt = 0; mt < 2; ++mt)
#pragma unroll
      for (int nt = 0; nt < 4; ++nt)
        acc[mt][nt] = __builtin_amdgcn_mfma_f32_16x16x32_bf16(a[mt], bc[nt], acc[mt][nt], 0, 0, 0);
  }
  __syncthreads();  // all waves done reading As

  // epilogue: bias + ELU -> bf16 back into As
#pragma unroll
  for (int nt = 0; nt < 4; ++nt) {
    int col = w * 64 + nt * 16 + lr;
    float bias = b1a[col];
#pragma unroll
    for (int mt = 0; mt < 2; ++mt)
#pragma unroll
      for (int j = 0; j < 4; ++j) {
        float v = elu_f(acc[mt][nt][j] + bias);
        As[(mt * 16 + lk * 4 + j) * LDA + col] = f2bf(v);
      }
  }
  __syncthreads();

  // segmented reduction over dst-runs; thread t owns column t.
  {
    const int col = t;
    float run = 0.f;
    int prev = dsts[0];
    int segstart = 0;
#pragma unroll 8
    for (int r = 0; r < EBR; ++r) {
      int d = dsts[r];
      if (d != prev) {
        if (segstart == 0)
          atomicAdd(&agg[(size_t)prev * 256 + col], run);
        else
          agg[(size_t)prev * 256 + col] = run;  // interior: sole owner
        run = 0.f;
        prev = d;
        segstart = r;
      }
      run += bf2f(As[r * LDA + col]);
    }
    atomicAdd(&agg[(size_t)prev * 256 + col], run);  // tail touches tile edge
  }
}

#define LDN 392  // 384 + 8 pad

// 64 nodes/block, 4 waves. [proven: unchanged since R10]
__global__ __launch_bounds__(256, 3) void node_mlp_kernel(
    const float* __restrict__ x, const float* __restrict__ agg,
    const int* __restrict__ startA, const float* __restrict__ b1b,
    const float* __restrict__ b2a, const float* __restrict__ b2b,
    const unsigned short* __restrict__ w1bP, const unsigned short* __restrict__ w2aP,
    const unsigned short* __restrict__ w2bP,
    float* __restrict__ out, int N) {
  __shared__ __align__(16) unsigned short As[64 * LDN];
  __shared__ float inv64[64];
  const int t = threadIdx.x;
  const int n0 = blockIdx.x * 64;

  const int w = t >> 6, l = t & 63;
  const int lr = l & 15, lk = l >> 4;
  const unsigned short* B0 = w1bP + (size_t)(w * 32) * 512 + (size_t)l * 8;
  const unsigned short* B1 = w2aP + (size_t)(w * 48) * 512 + (size_t)l * 8;
  const unsigned short* B2 = w2bP + (size_t)(w * 16) * 512 + (size_t)l * 8;

  if (t < 64) {
    int node = n0 + t;
    int cn = (node < N) ? (startA[node + 1] - startA[node]) : 0;
    inv64[t] = cn > 0 ? 1.0f / (float)cn : 0.f;
  }

  short8 bA[4], bB[4];
#pragma unroll
  for (int n = 0; n < 4; ++n) bA[n] = *(const short8*)(B0 + n * 4096);

  __syncthreads();  // inv64 ready

  // stage magg: [64][264] bf16 = agg[node]*inv
  for (int idx = t; idx < 64 * 64; idx += 256) {
    int nn = idx >> 6, c4 = idx & 63;
    int node = n0 + nn;
    fvec4 v = {0.f, 0.f, 0.f, 0.f};
    if (node < N) {
      float inv = inv64[nn];
      fvec4 a = *(const fvec4*)(agg + (size_t)node * 256 + c4 * 4);
      v.x = a.x * inv; v.y = a.y * inv; v.z = a.z * inv; v.w = a.w * inv;
    }
    us4 o;
    o.x = f2bf(v.x); o.y = f2bf(v.y); o.z = f2bf(v.z); o.w = f2bf(v.w);
    *(us4*)(&As[nn * 264 + c4 * 4]) = o;
  }
  __syncthreads();

  const f32x4 zero4 = {0.f, 0.f, 0.f, 0.f};
  f32x4 accU[4][4];
#pragma unroll
  for (int mt = 0; mt < 4; ++mt)
#pragma unroll
    for (int nt = 0; nt < 4; ++nt) accU[mt][nt] = zero4;

  // GEMM-u: magg[64,256] x W1b[256,256]
#pragma unroll
  for (int kt = 0; kt < 8; ++kt) {
    short8* bc = (kt & 1) ? bB : bA;
    short8* bn = (kt & 1) ? bA : bB;
    if (kt < 7) {
#pragma unroll
      for (int n = 0; n < 4; ++n) bn[n] = *(const short8*)(B0 + n * 4096 + (kt + 1) * 512);
    }
    short8 a[4];
#pragma unroll
    for (int mt = 0; mt < 4; ++mt)
      a[mt] = *(const short8*)(&As[(mt * 16 + lr) * 264 + kt * 32 + lk * 8]);
#pragma unroll
    for (int mt = 0; mt < 4; ++mt)
#pragma unroll
      for (int nt = 0; nt < 4; ++nt)
        accU[mt][nt] = __builtin_amdgcn_mfma_f32_16x16x32_bf16(a[mt], bc[nt], accU[mt][nt], 0, 0, 0);
  }

  // prefetch W2a kt=0
#pragma unroll
  for (int n = 0; n < 4; ++n) bA[n] = *(const short8*)(B1 + n * 6144);

  __syncthreads();  // magg reads done; As re-purposed at stride 392

  // stage x into cols [0,128) of the [64][392] buffer
  for (int idx = t; idx < 64 * 32; idx += 256) {
    int nn = idx >> 5, c4 = idx & 31;
    int node = n0 + nn;
    fvec4 v = {0.f, 0.f, 0.f, 0.f};
    if (node < N) v = *(const fvec4*)(x + (size_t)node * 128 + c4 * 4);
    us4 o;
    o.x = f2bf(v.x); o.y = f2bf(v.y); o.z = f2bf(v.z); o.w = f2bf(v.w);
    *(us4*)(&As[nn * LDN + c4 * 4]) = o;
  }

  // write u = accU + b1b (gated by cnt>0) into cols [128,384)
#pragma unroll
  for (int nt = 0; nt < 4; ++nt) {
    int col = w * 64 + nt * 16 + lr;
    float bias = b1b[col];
#pragma unroll
    for (int mt = 0; mt < 4; ++mt)
#pragma unroll
      for (int j = 0; j < 4; ++j) {
        int row = mt * 16 + lk * 4 + j;
        float g = inv64[row] > 0.f ? 1.f : 0.f;
        As[row * LDN + 128 + col] = f2bf(accU[mt][nt][j] + g * bias);
      }
  }
  __syncthreads();

  f32x4 acc[4][4];
#pragma unroll
  for (int mt = 0; mt < 4; ++mt)
#pragma unroll
    for (int nt = 0; nt < 4; ++nt) acc[mt][nt] = zero4;

  // MLP2 GEMM1: [64,384] x W2a[384,256]
#pragma unroll
  for (int kt = 0; kt < 12; ++kt) {
    short8* bc = (kt & 1) ? bB : bA;
    short8* bn = (kt & 1) ? bA : bB;
    if (kt < 11) {
#pragma unroll
      for (int n = 0; n < 4; ++n) bn[n] = *(const short8*)(B1 + n * 6144 + (kt + 1) * 512);
    }
    short8 a[4];
#pragma unroll
    for (int mt = 0; mt < 4; ++mt)
      a[mt] = *(const short8*)(&As[(mt * 16 + lr) * LDN + kt * 32 + lk * 8]);
#pragma unroll
    for (int mt = 0; mt < 4; ++mt)
#pragma unroll
      for (int nt = 0; nt < 4; ++nt)
        acc[mt][nt] = __builtin_amdgcn_mfma_f32_16x16x32_bf16(a[mt], bc[nt], acc[mt][nt], 0, 0, 0);
  }

#pragma unroll
  for (int n = 0; n < 2; ++n) bA[n] = *(const short8*)(B2 + n * 4096);

  __syncthreads();

  // epilogue1: bias + ELU -> H (reuse As, stride 264)
#pragma unroll
  for (int nt = 0; nt < 4; ++nt) {
    int col = w * 64 + nt * 16 + lr;
    float bias = b2a[col];
#pragma unroll
    for (int mt = 0; mt < 4; ++mt)
#pragma unroll
      for (int j = 0; j < 4; ++j) {
        float v = elu_f(acc[mt][nt][j] + bias);
        As[(mt * 16 + lk * 4 + j) * 264 + col] = f2bf(v);
      }
  }
  __syncthreads();

  // GEMM2: H[64,256] x W2b[256,128]; wave w owns cols [32w, 32w+32)
  f32x4 acc2[4][2];
#pragma unroll
  for (int mt = 0; mt < 4; ++mt)
#pragma unroll
    for (int nt = 0; nt < 2; ++nt) acc2[mt][nt] = zero4;
#pragma unroll
  for (int kt = 0; kt < 8; ++kt) {
    short8* bc = (kt & 1) ? bB : bA;
    short8* bn = (kt & 1) ? bA : bB;
    if (kt < 7) {
#pragma unroll
      for (int n = 0; n < 2; ++n) bn[n] = *(const short8*)(B2 + n * 4096 + (kt + 1) * 512);
    }
    short8 a[4];
#pragma unroll
    for (int mt = 0; mt < 4; ++mt)
      a[mt] = *(const short8*)(&As[(mt * 16 + lr) * 264 + kt * 32 + lk * 8]);
#pragma unroll
    for (int mt = 0; mt < 4; ++mt)
#pragma unroll
      for (int nt = 0; nt < 2; ++nt)
        acc2[mt][nt] = __builtin_amdgcn_mfma_f32_16x16x32_bf16(a[mt], bc[nt], acc2[mt][nt], 0, 0, 0);
  }

  // epilogue2: bias + store
#pragma unroll
  for (int nt = 0; nt < 2; ++nt) {
    int col = w * 32 + nt * 16 + lr;
    float bias = b2b[col];
#pragma unroll
    for (int mt = 0; mt < 4; ++mt)
#pragma unroll
      for (int j = 0; j < 4; ++j) {
        int node = n0 + mt * 16 + lk * 4 + j;
        if (node < N) out[(size_t)node * 128 + col] = acc2[mt][nt][j] + bias;
      }
  }
}

extern "C" void kernel_launch(void* const* d_in, const int* in_sizes, int n_in,
                              void* d_out, int out_size, void* d_ws, size_t ws_size,
                              hipStream_t stream) {
  const float* x = (const float*)d_in[0];
  const int* ei = (const int*)d_in[1];
  const float* eattr = (const float*)d_in[2];
  const float* W1a = (const float*)d_in[5];
  const float* b1a = (const float*)d_in[6];
  const float* W1b = (const float*)d_in[7];
  const float* b1b = (const float*)d_in[8];
  const float* W2a = (const float*)d_in[9];
  const float* b2a = (const float*)d_in[10];
  const float* W2b = (const float*)d_in[11];
  const float* b2b = (const float*)d_in[12];

  const int N = in_sizes[0] / 128;   // 25000
  const int E = in_sizes[2] / 128;   // 400000

  char* ws = (char*)d_ws;
  float* agg = (float*)ws;                              // N*256 f32 (sum of elu(h1))
  size_t off = (size_t)N * 256 * 4;
  int* cntbuf = (int*)(ws + off); off += (size_t)N * 4;
  int* startA = (int*)(ws + off); off += (size_t)(N + 1) * 4;
  int* offs   = (int*)(ws + off); off += (size_t)N * 4;
  int* eid    = (int*)(ws + off); off += (size_t)E * 4;
  off = (off + 255) & ~(size_t)255;
  unsigned short* xH   = (unsigned short*)(ws + off); off += (size_t)N * 128 * 2;
  unsigned short* w1aP = (unsigned short*)(ws + off); off += 256 * 256 * 2;
  unsigned short* w1bP = (unsigned short*)(ws + off); off += 256 * 256 * 2;
  unsigned short* w2aP = (unsigned short*)(ws + off); off += 384 * 256 * 2;
  unsigned short* w2bP = (unsigned short*)(ws + off);

  // zero only cnt via memset (100 KB); agg zero + xH convert run inside prep.
  (void)hipMemsetAsync(cntbuf, 0, (size_t)N * 4, stream);

  const int hb = (E + 255) / 256;                  // hist blocks
  const int aggN = N * 256;                        // f32 elements in agg
  const int xElems = N * 128;
  // tail range covers max(aggN/4, xElems/8) items (aggN/4 dominates)
  long tail = aggN / 4;
  if (xElems / 8 > tail) tail = xElems / 8;
  const int tb = (int)((tail + 255) / 256);

  prep_kernel<<<1024 + hb + tb, 256, 0, stream>>>(
      W1a, W1b, W2a, W2b, w1aP, w1bP, w2aP, w2bP, ei + E, cntbuf, E, hb,
      agg, aggN, x, xH, xElems);

  scan_kernel<<<1, 1024, 0, stream>>>(cntbuf, startA, offs, N, E);
  eid_kernel<<<hb, 256, 0, stream>>>(ei + E, offs, eid, E);

  edge_mlp_kernel<<<E / EBR, 256, 0, stream>>>(xH, ei, ei + E, eattr, b1a, w1aP, eid, agg);

  node_mlp_kernel<<<(N + 63) / 64, 256, 0, stream>>>(x, agg, startA, b1b, b2a, b2b,
                                                     w1bP, w2aP, w2bP, (float*)d_out, N);
}

// Round 19
// 261.218 us; speedup vs baseline: 1.7327x; 1.0122x over previous
//
#include <hip/hip_runtime.h>
#include <hip/hip_bf16.h>
#include <stdint.h>

typedef short short8 __attribute__((ext_vector_type(8)));
typedef float f32x4 __attribute__((ext_vector_type(4)));
typedef float fvec4 __attribute__((ext_vector_type(4)));
typedef unsigned short us4 __attribute__((ext_vector_type(4)));
typedef unsigned short us8 __attribute__((ext_vector_type(8)));

// native float->bf16 (RNE)
static __device__ __forceinline__ unsigned short f2bf(float f) {
  return __bfloat16_as_ushort(__float2bfloat16(f));
}

static __device__ __forceinline__ float bf2f(unsigned short u) {
  union { uint32_t u; float f; } v; v.u = (uint32_t)u << 16;
  return v.f;
}

// fast ELU: __expf -> v_exp_f32. |err| ~1e-7, fine vs 2e-2 threshold.
static __device__ __forceinline__ float elu_f(float v) {
  return v > 0.0f ? v : __expf(v) - 1.0f;
}

// Fused prep, three concurrent block ranges:
//   [0, 1024)        : pack all 4 weights into MFMA B-fragment order
//   [1024, 1024+hb)  : histogram dst counts
//   [1024+hb, ...)   : zero agg (N*256 f32) + convert x->xH (bf16)
__global__ void prep_kernel(const float* __restrict__ W1a, const float* __restrict__ W1b,
                            const float* __restrict__ W2a, const float* __restrict__ W2b,
                            unsigned short* __restrict__ w1aP, unsigned short* __restrict__ w1bP,
                            unsigned short* __restrict__ w2aP, unsigned short* __restrict__ w2bP,
                            const int* __restrict__ col_idx, int* __restrict__ cnt, int E,
                            int hb, float* __restrict__ agg, int aggN,
                            const float* __restrict__ x, unsigned short* __restrict__ xH,
                            int xElems) {
  int b = blockIdx.x;
  if (b < 1024) {
    int p = b * 256 + threadIdx.x;
    const float* W; unsigned short* dst; int KT, Nc, q;
    if (p < 65536)       { W = W1a; dst = w1aP; KT = 8;  Nc = 256; q = p; }
    else if (p < 131072) { W = W1b; dst = w1bP; KT = 8;  Nc = 256; q = p - 65536; }
    else if (p < 229376) { W = W2a; dst = w2aP; KT = 12; Nc = 256; q = p - 131072; }
    else                 { W = W2b; dst = w2bP; KT = 8;  Nc = 128; q = p - 229376; }
    int i = q & 7;
    int l = (q >> 3) & 63;
    int rest = q >> 9;
    int kt = rest % KT;
    int nt = rest / KT;
    dst[q] = f2bf(W[(size_t)(kt * 32 + (l >> 4) * 8 + i) * Nc + nt * 16 + (l & 15)]);
  } else if (b < 1024 + hb) {
    int i = (b - 1024) * 256 + threadIdx.x;
    if (i < E) atomicAdd(&cnt[col_idx[i]], 1);
  } else {
    int idx = (b - 1024 - hb) * 256 + threadIdx.x;
    if (idx * 4 < aggN) {
      fvec4 z = {0.f, 0.f, 0.f, 0.f};
      *(fvec4*)(agg + (size_t)idx * 4) = z;
    }
    if (idx * 8 < xElems) {
      const float* src = x + (size_t)idx * 8;
      fvec4 a = *(const fvec4*)src;
      fvec4 c = *(const fvec4*)(src + 4);
      us8 o;
      o[0] = f2bf(a.x); o[1] = f2bf(a.y); o[2] = f2bf(a.z); o[3] = f2bf(a.w);
      o[4] = f2bf(c.x); o[5] = f2bf(c.y); o[6] = f2bf(c.z); o[7] = f2bf(c.w);
      *(us8*)(xH + (size_t)idx * 8) = o;
    }
  }
}

// single-launch scan: each thread serially owns a chunk, one 1024-wide block scan.
__global__ __launch_bounds__(1024) void scan_kernel(const int* __restrict__ cnt,
                                                    int* __restrict__ startA,
                                                    int* __restrict__ offs, int N, int E) {
  __shared__ int partial[1024];
  const int t = threadIdx.x;
  const int chunk = (N + 1023) >> 10;
  const int base = t * chunk;
  int s = 0;
  for (int i = 0; i < chunk; ++i) {
    int idx = base + i;
    if (idx < N) s += cnt[idx];
  }
  partial[t] = s;
  __syncthreads();
  for (int o = 1; o < 1024; o <<= 1) {
    int a = (t >= o) ? partial[t - o] : 0;
    __syncthreads();
    partial[t] += a;
    __syncthreads();
  }
  int run = partial[t] - s;
  for (int i = 0; i < chunk; ++i) {
    int idx = base + i;
    if (idx < N) {
      startA[idx] = run;
      offs[idx] = run;
      run += cnt[idx];
    }
  }
  if (t == 0) startA[N] = E;
}

// dst-sorted edge list: eid[csr_slot] = edge
__global__ void eid_kernel(const int* __restrict__ col_idx, int* __restrict__ offs,
                           int* __restrict__ eid, int E) {
  int i = blockIdx.x * blockDim.x + threadIdx.x;
  if (i < E) eid[atomicAdd(&offs[col_idx[i]], 1)] = i;
}

#define LDA 264  // 256 + 8 pad (bf16 elems); 528B row stride, 16B aligned
#define EBR 32   // CSR slots per block

// 32 dst-sorted CSR slots/block, 4 waves. [proven: identical to R18's 143us kernel]
__global__ __launch_bounds__(256, 6) void edge_mlp_kernel(
    const unsigned short* __restrict__ xH, const int* __restrict__ row_idx,
    const int* __restrict__ col_idx, const float* __restrict__ eattr,
    const float* __restrict__ b1a, const unsigned short* __restrict__ w1aP,
    const int* __restrict__ eid, float* __restrict__ agg) {
  __shared__ __align__(16) unsigned short As[EBR * LDA];
  __shared__ int rowi[EBR];
  __shared__ int eidx[EBR];
  __shared__ int dsts[EBR];
  const int t = threadIdx.x;
  const int e0 = blockIdx.x * EBR;

  if (t < EBR) {
    int e = eid[e0 + t];
    eidx[t] = e;
    rowi[t] = row_idx[e];
    dsts[t] = col_idx[e];  // non-decreasing across the tile (CSR order)
  }

  const int w = t >> 6, l = t & 63;
  const int lr = l & 15, lk = l >> 4;
  const unsigned short* B1 = w1aP + (size_t)(w * 32) * 512 + (size_t)l * 8;

  short8 bA[4], bB[4];
#pragma unroll
  for (int n = 0; n < 4; ++n) bA[n] = *(const short8*)(B1 + n * 4096);

  __syncthreads();

  // stage x half: [32 rows][16 us8 chunks] from xH (bf16, cache-resident)
  for (int idx = t; idx < EBR * 16; idx += 256) {
    int r = idx >> 4, g = idx & 15;
    us8 v = *(const us8*)(xH + (size_t)rowi[r] * 128 + (size_t)g * 8);
    *(us8*)(&As[r * LDA + g * 8]) = v;
  }
  // stage eattr half: [32 rows][32 fvec4 chunks] f32 -> bf16 (cols 128..255)
  for (int idx = t; idx < EBR * 32; idx += 256) {
    int r = idx >> 5, c4 = idx & 31;
    fvec4 v = __builtin_nontemporal_load(
        (const fvec4*)(eattr + (size_t)eidx[r] * 128 + (size_t)c4 * 4));
    us4 o;
    o.x = f2bf(v.x); o.y = f2bf(v.y); o.z = f2bf(v.z); o.w = f2bf(v.w);
    *(us4*)(&As[r * LDA + 128 + c4 * 4]) = o;
  }
  __syncthreads();

  f32x4 acc[2][4];
  const f32x4 zero4 = {0.f, 0.f, 0.f, 0.f};
#pragma unroll
  for (int mt = 0; mt < 2; ++mt)
#pragma unroll
    for (int nt = 0; nt < 4; ++nt) acc[mt][nt] = zero4;

  // GEMM1: [32,256] x W1a[256,256], B double-buffered
#pragma unroll
  for (int kt = 0; kt < 8; ++kt) {
    short8* bc = (kt & 1) ? bB : bA;
    short8* bn = (kt & 1) ? bA : bB;
    if (kt < 7) {
#pragma unroll
      for (int n = 0; n < 4; ++n) bn[n] = *(const short8*)(B1 + n * 4096 + (kt + 1) * 512);
    }
    short8 a[2];
#pragma unroll
    for (int mt = 0; mt < 2; ++mt)
      a[mt] = *(const short8*)(&As[(mt * 16 + lr) * LDA + kt * 32 + lk * 8]);
#pragma unroll
    for (int mt = 0; mt < 2; ++mt)
#pragma unroll
      for (int nt = 0; nt < 4; ++nt)
        acc[mt][nt] = __builtin_amdgcn_mfma_f32_16x16x32_bf16(a[mt], bc[nt], acc[mt][nt], 0, 0, 0);
  }
  __syncthreads();  // all waves done reading As

  // epilogue: bias + ELU -> bf16 back into As
#pragma unroll
  for (int nt = 0; nt < 4; ++nt) {
    int col = w * 64 + nt * 16 + lr;
    float bias = b1a[col];
#pragma unroll
    for (int mt = 0; mt < 2; ++mt)
#pragma unroll
      for (int j = 0; j < 4; ++j) {
        float v = elu_f(acc[mt][nt][j] + bias);
        As[(mt * 16 + lk * 4 + j) * LDA + col] = f2bf(v);
      }
  }
  __syncthreads();

  // segmented reduction over dst-runs; thread t owns column t.
  {
    const int col = t;
    float run = 0.f;
    int prev = dsts[0];
    int segstart = 0;
#pragma unroll 8
    for (int r = 0; r < EBR; ++r) {
      int d = dsts[r];
      if (d != prev) {
        if (segstart == 0)
          atomicAdd(&agg[(size_t)prev * 256 + col], run);
        else
          agg[(size_t)prev * 256 + col] = run;  // interior: sole owner
        run = 0.f;
        prev = d;
        segstart = r;
      }
      run += bf2f(As[r * LDA + col]);
    }
    atomicAdd(&agg[(size_t)prev * 256 + col], run);  // tail touches tile edge
  }
}

#define LDN 392  // 384 + 8 pad
#define NB 32    // nodes per block (32-row node structure validated by R15)

// 32 nodes/block, 4 waves; grid 782 -> shorter latency-bound tail than 64-row.
// Phase A: magg = agg/cnt -> GEMM x W1b -> u (+b1b, gated).
// Phase B: [xH | u] -> MLP2 (GEMM 384->256, ELU, GEMM 256->128).
__global__ __launch_bounds__(256, 4) void node_mlp_kernel(
    const unsigned short* __restrict__ xH, const float* __restrict__ agg,
    const int* __restrict__ startA, const float* __restrict__ b1b,
    const float* __restrict__ b2a, const float* __restrict__ b2b,
    const unsigned short* __restrict__ w1bP, const unsigned short* __restrict__ w2aP,
    const unsigned short* __restrict__ w2bP,
    float* __restrict__ out, int N) {
  __shared__ __align__(16) unsigned short As[NB * LDN];
  __shared__ float inv32[NB];
  const int t = threadIdx.x;
  const int n0 = blockIdx.x * NB;

  const int w = t >> 6, l = t & 63;
  const int lr = l & 15, lk = l >> 4;
  const unsigned short* B0 = w1bP + (size_t)(w * 32) * 512 + (size_t)l * 8;
  const unsigned short* B1 = w2aP + (size_t)(w * 48) * 512 + (size_t)l * 8;
  const unsigned short* B2 = w2bP + (size_t)(w * 16) * 512 + (size_t)l * 8;

  if (t < NB) {
    int node = n0 + t;
    int cn = (node < N) ? (startA[node + 1] - startA[node]) : 0;
    inv32[t] = cn > 0 ? 1.0f / (float)cn : 0.f;
  }

  short8 bA[4], bB[4];
#pragma unroll
  for (int n = 0; n < 4; ++n) bA[n] = *(const short8*)(B0 + n * 4096);

  __syncthreads();  // inv32 ready

  // stage magg: [32][264] bf16 = agg[node]*inv
  for (int idx = t; idx < NB * 64; idx += 256) {
    int nn = idx >> 6, c4 = idx & 63;
    int node = n0 + nn;
    fvec4 v = {0.f, 0.f, 0.f, 0.f};
    if (node < N) {
      float inv = inv32[nn];
      fvec4 a = *(const fvec4*)(agg + (size_t)node * 256 + c4 * 4);
      v.x = a.x * inv; v.y = a.y * inv; v.z = a.z * inv; v.w = a.w * inv;
    }
    us4 o;
    o.x = f2bf(v.x); o.y = f2bf(v.y); o.z = f2bf(v.z); o.w = f2bf(v.w);
    *(us4*)(&As[nn * 264 + c4 * 4]) = o;
  }
  __syncthreads();

  const f32x4 zero4 = {0.f, 0.f, 0.f, 0.f};
  f32x4 accU[2][4];
#pragma unroll
  for (int mt = 0; mt < 2; ++mt)
#pragma unroll
    for (int nt = 0; nt < 4; ++nt) accU[mt][nt] = zero4;

  // GEMM-u: magg[32,256] x W1b[256,256]
#pragma unroll
  for (int kt = 0; kt < 8; ++kt) {
    short8* bc = (kt & 1) ? bB : bA;
    short8* bn = (kt & 1) ? bA : bB;
    if (kt < 7) {
#pragma unroll
      for (int n = 0; n < 4; ++n) bn[n] = *(const short8*)(B0 + n * 4096 + (kt + 1) * 512);
    }
    short8 a[2];
#pragma unroll
    for (int mt = 0; mt < 2; ++mt)
      a[mt] = *(const short8*)(&As[(mt * 16 + lr) * 264 + kt * 32 + lk * 8]);
#pragma unroll
    for (int mt = 0; mt < 2; ++mt)
#pragma unroll
      for (int nt = 0; nt < 4; ++nt)
        accU[mt][nt] = __builtin_amdgcn_mfma_f32_16x16x32_bf16(a[mt], bc[nt], accU[mt][nt], 0, 0, 0);
  }

  // prefetch W2a kt=0
#pragma unroll
  for (int n = 0; n < 4; ++n) bA[n] = *(const short8*)(B1 + n * 6144);

  __syncthreads();  // magg reads done; As re-purposed at stride 392

  // stage xH into cols [0,128) of the [32][392] buffer (us8 copies, bf16)
  for (int idx = t; idx < NB * 16; idx += 256) {
    int nn = idx >> 4, g = idx & 15;
    int node = n0 + nn;
    us8 v = {0, 0, 0, 0, 0, 0, 0, 0};
    if (node < N) v = *(const us8*)(xH + (size_t)node * 128 + (size_t)g * 8);
    *(us8*)(&As[nn * LDN + g * 8]) = v;
  }

  // write u = accU + b1b (gated by cnt>0) into cols [128,384)
#pragma unroll
  for (int nt = 0; nt < 4; ++nt) {
    int col = w * 64 + nt * 16 + lr;
    float bias = b1b[col];
#pragma unroll
    for (int mt = 0; mt < 2; ++mt)
#pragma unroll
      for (int j = 0; j < 4; ++j) {
        int row = mt * 16 + lk * 4 + j;
        float g = inv32[row] > 0.f ? 1.f : 0.f;
        As[row * LDN + 128 + col] = f2bf(accU[mt][nt][j] + g * bias);
      }
  }
  __syncthreads();

  f32x4 acc[2][4];
#pragma unroll
  for (int mt = 0; mt < 2; ++mt)
#pragma unroll
    for (int nt = 0; nt < 4; ++nt) acc[mt][nt] = zero4;

  // MLP2 GEMM1: [32,384] x W2a[384,256]
#pragma unroll
  for (int kt = 0; kt < 12; ++kt) {
    short8* bc = (kt & 1) ? bB : bA;
    short8* bn = (kt & 1) ? bA : bB;
    if (kt < 11) {
#pragma unroll
      for (int n = 0; n < 4; ++n) bn[n] = *(const short8*)(B1 + n * 6144 + (kt + 1) * 512);
    }
    short8 a[2];
#pragma unroll
    for (int mt = 0; mt < 2; ++mt)
      a[mt] = *(const short8*)(&As[(mt * 16 + lr) * LDN + kt * 32 + lk * 8]);
#pragma unroll
    for (int mt = 0; mt < 2; ++mt)
#pragma unroll
      for (int nt = 0; nt < 4; ++nt)
        acc[mt][nt] = __builtin_amdgcn_mfma_f32_16x16x32_bf16(a[mt], bc[nt], acc[mt][nt], 0, 0, 0);
  }

#pragma unroll
  for (int n = 0; n < 2; ++n) bA[n] = *(const short8*)(B2 + n * 4096);

  __syncthreads();

  // epilogue1: bias + ELU -> H (reuse As, stride 264)
#pragma unroll
  for (int nt = 0; nt < 4; ++nt) {
    int col = w * 64 + nt * 16 + lr;
    float bias = b2a[col];
#pragma unroll
    for (int mt = 0; mt < 2; ++mt)
#pragma unroll
      for (int j = 0; j < 4; ++j) {
        float v = elu_f(acc[mt][nt][j] + bias);
        As[(mt * 16 + lk * 4 + j) * 264 + col] = f2bf(v);
      }
  }
  __syncthreads();

  // GEMM2: H[32,256] x W2b[256,128]; wave w owns cols [32w, 32w+32)
  f32x4 acc2[2][2];
#pragma unroll
  for (int mt = 0; mt < 2; ++mt)
#pragma unroll
    for (int nt = 0; nt < 2; ++nt) acc2[mt][nt] = zero4;
#pragma unroll
  for (int kt = 0; kt < 8; ++kt) {
    short8* bc = (kt & 1) ? bB : bA;
    short8* bn = (kt & 1) ? bA : bB;
    if (kt < 7) {
#pragma unroll
      for (int n = 0; n < 2; ++n) bn[n] = *(const short8*)(B2 + n * 4096 + (kt + 1) * 512);
    }
    short8 a[2];
#pragma unroll
    for (int mt = 0; mt < 2; ++mt)
      a[mt] = *(const short8*)(&As[(mt * 16 + lr) * 264 + kt * 32 + lk * 8]);
#pragma unroll
    for (int mt = 0; mt < 2; ++mt)
#pragma unroll
      for (int nt = 0; nt < 2; ++nt)
        acc2[mt][nt] = __builtin_amdgcn_mfma_f32_16x16x32_bf16(a[mt], bc[nt], acc2[mt][nt], 0, 0, 0);
  }

  // epilogue2: bias + store
#pragma unroll
  for (int nt = 0; nt < 2; ++nt) {
    int col = w * 32 + nt * 16 + lr;
    float bias = b2b[col];
#pragma unroll
    for (int mt = 0; mt < 2; ++mt)
#pragma unroll
      for (int j = 0; j < 4; ++j) {
        int node = n0 + mt * 16 + lk * 4 + j;
        if (node < N) out[(size_t)node * 128 + col] = acc2[mt][nt][j] + bias;
      }
  }
}

extern "C" void kernel_launch(void* const* d_in, const int* in_sizes, int n_in,
                              void* d_out, int out_size, void* d_ws, size_t ws_size,
                              hipStream_t stream) {
  const float* x = (const float*)d_in[0];
  const int* ei = (const int*)d_in[1];
  const float* eattr = (const float*)d_in[2];
  const float* W1a = (const float*)d_in[5];
  const float* b1a = (const float*)d_in[6];
  const float* W1b = (const float*)d_in[7];
  const float* b1b = (const float*)d_in[8];
  const float* W2a = (const float*)d_in[9];
  const float* b2a = (const float*)d_in[10];
  const float* W2b = (const float*)d_in[11];
  const float* b2b = (const float*)d_in[12];

  const int N = in_sizes[0] / 128;   // 25000
  const int E = in_sizes[2] / 128;   // 400000

  char* ws = (char*)d_ws;
  float* agg = (float*)ws;                              // N*256 f32 (sum of elu(h1))
  size_t off = (size_t)N * 256 * 4;
  int* cntbuf = (int*)(ws + off); off += (size_t)N * 4;
  int* startA = (int*)(ws + off); off += (size_t)(N + 1) * 4;
  int* offs   = (int*)(ws + off); off += (size_t)N * 4;
  int* eid    = (int*)(ws + off); off += (size_t)E * 4;
  off = (off + 255) & ~(size_t)255;
  unsigned short* xH   = (unsigned short*)(ws + off); off += (size_t)N * 128 * 2;
  unsigned short* w1aP = (unsigned short*)(ws + off); off += 256 * 256 * 2;
  unsigned short* w1bP = (unsigned short*)(ws + off); off += 256 * 256 * 2;
  unsigned short* w2aP = (unsigned short*)(ws + off); off += 384 * 256 * 2;
  unsigned short* w2bP = (unsigned short*)(ws + off);

  // zero only cnt via memset (100 KB); agg zero + xH convert run inside prep.
  (void)hipMemsetAsync(cntbuf, 0, (size_t)N * 4, stream);

  const int hb = (E + 255) / 256;                  // hist blocks
  const int aggN = N * 256;                        // f32 elements in agg
  const int xElems = N * 128;
  long tail = aggN / 4;
  if (xElems / 8 > tail) tail = xElems / 8;
  const int tb = (int)((tail + 255) / 256);

  prep_kernel<<<1024 + hb + tb, 256, 0, stream>>>(
      W1a, W1b, W2a, W2b, w1aP, w1bP, w2aP, w2bP, ei + E, cntbuf, E, hb,
      agg, aggN, x, xH, xElems);

  scan_kernel<<<1, 1024, 0, stream>>>(cntbuf, startA, offs, N, E);
  eid_kernel<<<hb, 256, 0, stream>>>(ei + E, offs, eid, E);

  edge_mlp_kernel<<<E / EBR, 256, 0, stream>>>(xH, ei, ei + E, eattr, b1a, w1aP, eid, agg);

  node_mlp_kernel<<<(N + NB - 1) / NB, 256, 0, stream>>>(xH, agg, startA, b1b, b2a, b2b,
                                                         w1bP, w2aP, w2bP, (float*)d_out, N);
}